// Round 1
// baseline (17592.418 us; speedup 1.0000x reference)
//
#include <hip/hip_runtime.h>

#define T_LEN 512
#define BATCH 128
#define HID   256
#define G4    1024   // 4*H
#define NB    4      // batch rows per recurrence block
#define CHUNK 128    // time chunk for layer-1 pipeline

__device__ __forceinline__ float sigmf(float x){ return 1.0f/(1.0f + __expf(-x)); }
__device__ __forceinline__ float tanhf_(float x){ return 1.0f - 2.0f/(1.0f + __expf(2.0f*x)); }

// transpose [nmat][G][K] -> [nmat][K][G]
__global__ void k_transpose(const float* __restrict__ in, float* __restrict__ out,
                            int G, int K, int total){
  int idx = blockIdx.x*256 + threadIdx.x;
  if (idx >= total) return;
  int gk = G*K;
  int d = idx / gk;
  int r = idx - d*gk;
  int k = r / G;
  int g = r - k*G;
  out[idx] = in[d*gk + g*K + k];
}

// ---------------- layer 0: fused input-proj + recurrence, both dirs ----------------
// grid: 64 blocks (dir = bx>>5, batch block = bx&31), 256 threads
__global__ __launch_bounds__(256) void k_layer0(const float* __restrict__ x,      // [128][512][4]
                                                const float* __restrict__ w_ih,   // [2][1024][4]
                                                const float* __restrict__ whhT,   // [2][256][1024]
                                                const float* __restrict__ bias,   // [2][1024]
                                                float* __restrict__ y0)           // [512][128][512]
{
  const int tid = threadIdx.x;
  const int dir = blockIdx.x >> 5;
  const int b0  = (blockIdx.x & 31) * NB;
  const int g0  = tid << 2;

  __shared__ float h_lds[NB][HID];
  __shared__ float c_lds[NB][HID];
  __shared__ float g_lds[NB][G4];

  float4 wi0 = *(const float4*)&w_ih[(dir*G4 + g0 + 0)*4];
  float4 wi1 = *(const float4*)&w_ih[(dir*G4 + g0 + 1)*4];
  float4 wi2 = *(const float4*)&w_ih[(dir*G4 + g0 + 2)*4];
  float4 wi3 = *(const float4*)&w_ih[(dir*G4 + g0 + 3)*4];
  float4 bv  = *(const float4*)&bias[dir*G4 + g0];

  for (int i = tid; i < NB*HID; i += 256){
    ((float*)h_lds)[i] = 0.0f;
    ((float*)c_lds)[i] = 0.0f;
  }
  __syncthreads();

  const float* wT = whhT + dir*(HID*G4);

  for (int tt = 0; tt < T_LEN; ++tt){
    const int t = dir ? (T_LEN-1-tt) : tt;

    float a0[NB], a1[NB], a2[NB], a3[NB];
    #pragma unroll
    for (int b = 0; b < NB; ++b){
      float4 xv = *(const float4*)&x[((b0+b)*T_LEN + t)*4];
      a0[b] = bv.x + wi0.x*xv.x + wi0.y*xv.y + wi0.z*xv.z + wi0.w*xv.w;
      a1[b] = bv.y + wi1.x*xv.x + wi1.y*xv.y + wi1.z*xv.z + wi1.w*xv.w;
      a2[b] = bv.z + wi2.x*xv.x + wi2.y*xv.y + wi2.z*xv.z + wi2.w*xv.w;
      a3[b] = bv.w + wi3.x*xv.x + wi3.y*xv.y + wi3.z*xv.z + wi3.w*xv.w;
    }

    #pragma unroll 2
    for (int k0 = 0; k0 < HID; k0 += 4){
      float4 w0 = *(const float4*)&wT[(k0+0)*G4 + g0];
      float4 w1 = *(const float4*)&wT[(k0+1)*G4 + g0];
      float4 w2 = *(const float4*)&wT[(k0+2)*G4 + g0];
      float4 w3 = *(const float4*)&wT[(k0+3)*G4 + g0];
      #pragma unroll
      for (int b = 0; b < NB; ++b){
        float4 hv = *(const float4*)&h_lds[b][k0];
        a0[b] = fmaf(w0.x,hv.x, fmaf(w1.x,hv.y, fmaf(w2.x,hv.z, fmaf(w3.x,hv.w, a0[b]))));
        a1[b] = fmaf(w0.y,hv.x, fmaf(w1.y,hv.y, fmaf(w2.y,hv.z, fmaf(w3.y,hv.w, a1[b]))));
        a2[b] = fmaf(w0.z,hv.x, fmaf(w1.z,hv.y, fmaf(w2.z,hv.z, fmaf(w3.z,hv.w, a2[b]))));
        a3[b] = fmaf(w0.w,hv.x, fmaf(w1.w,hv.y, fmaf(w2.w,hv.z, fmaf(w3.w,hv.w, a3[b]))));
      }
    }

    #pragma unroll
    for (int b = 0; b < NB; ++b)
      *(float4*)&g_lds[b][g0] = make_float4(a0[b], a1[b], a2[b], a3[b]);
    __syncthreads();

    { // h/c update: thread -> (batch bb, h-slice j4..j4+3)
      const int bb = tid >> 6;
      const int j4 = (tid & 63) << 2;
      float4 iv = *(const float4*)&g_lds[bb][0*HID + j4];
      float4 fv = *(const float4*)&g_lds[bb][1*HID + j4];
      float4 gv = *(const float4*)&g_lds[bb][2*HID + j4];
      float4 ov = *(const float4*)&g_lds[bb][3*HID + j4];
      float4 cv = *(const float4*)&c_lds[bb][j4];
      float4 cn, hn;
      cn.x = sigmf(fv.x)*cv.x + sigmf(iv.x)*tanhf_(gv.x);  hn.x = sigmf(ov.x)*tanhf_(cn.x);
      cn.y = sigmf(fv.y)*cv.y + sigmf(iv.y)*tanhf_(gv.y);  hn.y = sigmf(ov.y)*tanhf_(cn.y);
      cn.z = sigmf(fv.z)*cv.z + sigmf(iv.z)*tanhf_(gv.z);  hn.z = sigmf(ov.z)*tanhf_(cn.z);
      cn.w = sigmf(fv.w)*cv.w + sigmf(iv.w)*tanhf_(gv.w);  hn.w = sigmf(ov.w)*tanhf_(cn.w);
      *(float4*)&c_lds[bb][j4] = cn;
      *(float4*)&h_lds[bb][j4] = hn;
      *(float4*)&y0[((size_t)t*BATCH + (b0+bb))*(2*HID) + dir*HID + j4] = hn;
    }
    __syncthreads();
  }
}

// ---------------- layer 1 forward recurrence over one time chunk ----------------
// grid: 32 blocks (batch blocks), 256 threads. Input gates precomputed in xp.
__global__ __launch_bounds__(256) void k_layer1(const float* __restrict__ xp,    // [CHUNK][128][1024]
                                                const float* __restrict__ whhT,  // [256][1024]
                                                float* __restrict__ hS,          // [128][256]
                                                float* __restrict__ cS,          // [128][256]
                                                int first)
{
  const int tid = threadIdx.x;
  const int b0  = blockIdx.x * NB;
  const int g0  = tid << 2;

  __shared__ float h_lds[NB][HID];
  __shared__ float c_lds[NB][HID];
  __shared__ float g_lds[NB][G4];

  if (first){
    for (int i = tid; i < NB*HID; i += 256){ ((float*)h_lds)[i]=0.0f; ((float*)c_lds)[i]=0.0f; }
  } else {
    for (int i = tid; i < NB*HID; i += 256){
      int b = i >> 8, j = i & (HID-1);
      ((float*)h_lds)[i] = hS[(b0+b)*HID + j];
      ((float*)c_lds)[i] = cS[(b0+b)*HID + j];
    }
  }
  __syncthreads();

  for (int tt = 0; tt < CHUNK; ++tt){
    float a0[NB], a1[NB], a2[NB], a3[NB];
    #pragma unroll
    for (int b = 0; b < NB; ++b){
      float4 g4v = *(const float4*)&xp[((size_t)tt*BATCH + (b0+b))*G4 + g0];
      a0[b]=g4v.x; a1[b]=g4v.y; a2[b]=g4v.z; a3[b]=g4v.w;
    }

    #pragma unroll 2
    for (int k0 = 0; k0 < HID; k0 += 4){
      float4 w0 = *(const float4*)&whhT[(k0+0)*G4 + g0];
      float4 w1 = *(const float4*)&whhT[(k0+1)*G4 + g0];
      float4 w2 = *(const float4*)&whhT[(k0+2)*G4 + g0];
      float4 w3 = *(const float4*)&whhT[(k0+3)*G4 + g0];
      #pragma unroll
      for (int b = 0; b < NB; ++b){
        float4 hv = *(const float4*)&h_lds[b][k0];
        a0[b] = fmaf(w0.x,hv.x, fmaf(w1.x,hv.y, fmaf(w2.x,hv.z, fmaf(w3.x,hv.w, a0[b]))));
        a1[b] = fmaf(w0.y,hv.x, fmaf(w1.y,hv.y, fmaf(w2.y,hv.z, fmaf(w3.y,hv.w, a1[b]))));
        a2[b] = fmaf(w0.z,hv.x, fmaf(w1.z,hv.y, fmaf(w2.z,hv.z, fmaf(w3.z,hv.w, a2[b]))));
        a3[b] = fmaf(w0.w,hv.x, fmaf(w1.w,hv.y, fmaf(w2.w,hv.z, fmaf(w3.w,hv.w, a3[b]))));
      }
    }

    #pragma unroll
    for (int b = 0; b < NB; ++b)
      *(float4*)&g_lds[b][g0] = make_float4(a0[b], a1[b], a2[b], a3[b]);
    __syncthreads();

    {
      const int bb = tid >> 6;
      const int j4 = (tid & 63) << 2;
      float4 iv = *(const float4*)&g_lds[bb][0*HID + j4];
      float4 fv = *(const float4*)&g_lds[bb][1*HID + j4];
      float4 gv = *(const float4*)&g_lds[bb][2*HID + j4];
      float4 ov = *(const float4*)&g_lds[bb][3*HID + j4];
      float4 cv = *(const float4*)&c_lds[bb][j4];
      float4 cn, hn;
      cn.x = sigmf(fv.x)*cv.x + sigmf(iv.x)*tanhf_(gv.x);  hn.x = sigmf(ov.x)*tanhf_(cn.x);
      cn.y = sigmf(fv.y)*cv.y + sigmf(iv.y)*tanhf_(gv.y);  hn.y = sigmf(ov.y)*tanhf_(cn.y);
      cn.z = sigmf(fv.z)*cv.z + sigmf(iv.z)*tanhf_(gv.z);  hn.z = sigmf(ov.z)*tanhf_(cn.z);
      cn.w = sigmf(fv.w)*cv.w + sigmf(iv.w)*tanhf_(gv.w);  hn.w = sigmf(ov.w)*tanhf_(cn.w);
      *(float4*)&c_lds[bb][j4] = cn;
      *(float4*)&h_lds[bb][j4] = hn;
    }
    __syncthreads();
  }

  for (int i = tid; i < NB*HID; i += 256){
    int b = i >> 8, j = i & (HID-1);
    hS[(b0+b)*HID + j] = ((float*)h_lds)[i];
    cS[(b0+b)*HID + j] = ((float*)c_lds)[i];
  }
}

// ---------------- fp32 tiled GEMM: C[M][1024] = A[M][512] * B[1024][512]^T + bias ----------------
// grid: (16, M/64), 256 threads, 64x64 tile, 4x4 per thread
__global__ __launch_bounds__(256) void k_gemm(const float* __restrict__ A,
                                              const float* __restrict__ B,
                                              const float* __restrict__ bias,
                                              float* __restrict__ C)
{
  __shared__ float As[16][68];
  __shared__ float Bs[16][68];
  const int tid = threadIdx.x;
  const int n0 = blockIdx.x * 64;
  const size_t m0 = (size_t)blockIdx.y * 64;
  const int tx = tid & 15, ty = tid >> 4;
  const int lr = tid >> 2, lk = (tid & 3) << 2;
  float acc[4][4] = {};

  for (int k0 = 0; k0 < 512; k0 += 16){
    float4 av = *(const float4*)&A[(m0 + lr)*512 + k0 + lk];
    float4 bw = *(const float4*)&B[(size_t)(n0 + lr)*512 + k0 + lk];
    As[lk+0][lr]=av.x; As[lk+1][lr]=av.y; As[lk+2][lr]=av.z; As[lk+3][lr]=av.w;
    Bs[lk+0][lr]=bw.x; Bs[lk+1][lr]=bw.y; Bs[lk+2][lr]=bw.z; Bs[lk+3][lr]=bw.w;
    __syncthreads();
    #pragma unroll
    for (int k = 0; k < 16; ++k){
      float4 a4 = *(const float4*)&As[k][ty<<2];
      float4 b4 = *(const float4*)&Bs[k][tx<<2];
      acc[0][0]=fmaf(a4.x,b4.x,acc[0][0]); acc[0][1]=fmaf(a4.x,b4.y,acc[0][1]);
      acc[0][2]=fmaf(a4.x,b4.z,acc[0][2]); acc[0][3]=fmaf(a4.x,b4.w,acc[0][3]);
      acc[1][0]=fmaf(a4.y,b4.x,acc[1][0]); acc[1][1]=fmaf(a4.y,b4.y,acc[1][1]);
      acc[1][2]=fmaf(a4.y,b4.z,acc[1][2]); acc[1][3]=fmaf(a4.y,b4.w,acc[1][3]);
      acc[2][0]=fmaf(a4.z,b4.x,acc[2][0]); acc[2][1]=fmaf(a4.z,b4.y,acc[2][1]);
      acc[2][2]=fmaf(a4.z,b4.z,acc[2][2]); acc[2][3]=fmaf(a4.z,b4.w,acc[2][3]);
      acc[3][0]=fmaf(a4.w,b4.x,acc[3][0]); acc[3][1]=fmaf(a4.w,b4.y,acc[3][1]);
      acc[3][2]=fmaf(a4.w,b4.z,acc[3][2]); acc[3][3]=fmaf(a4.w,b4.w,acc[3][3]);
    }
    __syncthreads();
  }

  float4 bb = *(const float4*)&bias[n0 + (tx<<2)];
  #pragma unroll
  for (int i = 0; i < 4; ++i){
    float4 o;
    o.x = acc[i][0] + bb.x; o.y = acc[i][1] + bb.y;
    o.z = acc[i][2] + bb.z; o.w = acc[i][3] + bb.w;
    *(float4*)&C[(m0 + (ty<<2) + i)*1024 + n0 + (tx<<2)] = o;
  }
}

// ---------------- final: layer-1 bwd single step + combine + out proj + softmax ----------------
__global__ __launch_bounds__(256) void k_final(const float* __restrict__ hS,    // [128][256] (fwd final h)
                                               const float* __restrict__ xp1b,  // [128][1024]
                                               const float* __restrict__ w_out, // [3][256]
                                               const float* __restrict__ b_out, // [3]
                                               float* __restrict__ out)         // [128][3]
{
  const int b = blockIdx.x, j = threadIdx.x;
  float iv = xp1b[b*G4 + 0*HID + j];
  float gv = xp1b[b*G4 + 2*HID + j];
  float ov = xp1b[b*G4 + 3*HID + j];
  float c  = sigmf(iv)*tanhf_(gv);            // c0 = 0, forget term vanishes
  float hb = sigmf(ov)*tanhf_(c);
  float last = hS[b*HID + j] + hb;

  __shared__ float part[3][256];
  part[0][j] = last * w_out[0*HID + j];
  part[1][j] = last * w_out[1*HID + j];
  part[2][j] = last * w_out[2*HID + j];
  __syncthreads();
  for (int s = 128; s > 0; s >>= 1){
    if (j < s){
      part[0][j] += part[0][j+s];
      part[1][j] += part[1][j+s];
      part[2][j] += part[2][j+s];
    }
    __syncthreads();
  }
  if (j == 0){
    float l0 = part[0][0] + b_out[0];
    float l1 = part[1][0] + b_out[1];
    float l2 = part[2][0] + b_out[2];
    float m = fmaxf(l0, fmaxf(l1, l2));
    float e0 = __expf(l0-m), e1 = __expf(l1-m), e2 = __expf(l2-m);
    float s = e0 + e1 + e2;
    out[b*3+0] = e0/s; out[b*3+1] = e1/s; out[b*3+2] = e2/s;
  }
}

extern "C" void kernel_launch(void* const* d_in, const int* in_sizes, int n_in,
                              void* d_out, int out_size, void* d_ws, size_t ws_size,
                              hipStream_t stream) {
  const float* x     = (const float*)d_in[0];
  const float* w_ih0 = (const float*)d_in[1];
  const float* w_hh0 = (const float*)d_in[2];
  const float* b0p   = (const float*)d_in[3];
  const float* w_ih1 = (const float*)d_in[4];
  const float* w_hh1 = (const float*)d_in[5];
  const float* b1p   = (const float*)d_in[6];
  const float* w_out = (const float*)d_in[7];
  const float* b_out = (const float*)d_in[8];
  float* out = (float*)d_out;

  // workspace layout (floats)
  float* ws    = (float*)d_ws;
  float* y0    = ws;                                   // 512*128*512   = 33,554,432
  float* xp1c  = y0    + (size_t)T_LEN*BATCH*2*HID;    // CHUNK*128*1024= 16,777,216
  float* whhT0 = xp1c  + (size_t)CHUNK*BATCH*G4;       // 2*256*1024
  float* whhT1 = whhT0 + 2*HID*G4;                     // 256*1024
  float* xp1b  = whhT1 + HID*G4;                       // 128*1024
  float* h1s   = xp1b  + BATCH*G4;                     // 128*256
  float* c1s   = h1s   + BATCH*HID;                    // 128*256

  // prep: transpose recurrent weights to [K][G]
  k_transpose<<<(2*G4*HID+255)/256, 256, 0, stream>>>(w_hh0, whhT0, G4, HID, 2*G4*HID);
  k_transpose<<<(G4*HID+255)/256, 256, 0, stream>>>(w_hh1, whhT1, G4, HID, G4*HID);

  // layer 0 (both directions) -> y0
  k_layer0<<<64, 256, 0, stream>>>(x, w_ih0, whhT0, b0p, y0);

  // layer-1 backward only needs its first step: xp1b = y0[511] @ w_ih1[1]^T + b1[1]
  k_gemm<<<dim3(16, 2), 256, 0, stream>>>(y0 + (size_t)(T_LEN-1)*BATCH*2*HID,
                                          w_ih1 + (size_t)G4*2*HID, b1p + G4, xp1b);

  // layer 1 forward, chunked: xp1 chunk GEMM then recurrence chunk
  for (int c = 0; c < T_LEN/CHUNK; ++c){
    k_gemm<<<dim3(16, CHUNK*BATCH/64), 256, 0, stream>>>(
        y0 + (size_t)c*CHUNK*BATCH*2*HID, w_ih1, b1p, xp1c);
    k_layer1<<<32, 256, 0, stream>>>(xp1c, whhT1, h1s, c1s, c == 0 ? 1 : 0);
  }

  // combine + output projection + softmax
  k_final<<<BATCH, 256, 0, stream>>>(h1s, xp1b, w_out, b_out, out);
}

// Round 2
// 10296.934 us; speedup vs baseline: 1.7085x; 1.7085x over previous
//
#include <hip/hip_runtime.h>

typedef __attribute__((ext_vector_type(8))) short bf16x8;
typedef __attribute__((ext_vector_type(4))) float f32x4;

#define T_LEN 512
#define BATCH 128
#define HID   256
#define G4    1024
#define NB    16
#define WPACK_STRIDE (4*16*9*64*8)   // 294912 bf16 per dir-layer

__device__ __forceinline__ float sigmf(float x){ return 1.0f/(1.0f + __expf(-x)); }
__device__ __forceinline__ float tanhf_(float x){ return 1.0f - 2.0f/(1.0f + __expf(2.0f*x)); }

__device__ __forceinline__ unsigned short f2bf(float f){
  union{float f;unsigned u;} v; v.f=f;
  unsigned r = v.u + 0x7FFF + ((v.u>>16)&1);
  return (unsigned short)(r>>16);
}
__device__ __forceinline__ float bf2f(unsigned short b){
  union{unsigned u;float f;} v; v.u = ((unsigned)b)<<16; return v.f;
}

// ---- pack recurrent weights into B-fragment stream order ----
// wpack[dl][w][nt][kk][lane][8] ; dl: 0=l0 fwd, 1=l0 bwd, 2=l1 fwd
// B[k][n]: n = w*256+nt*16+(lane&15), k = kk*32+(lane>>4)*8+j
// layer0: k<256 -> w_hh ; 256..259 -> w_ih ; 260 -> bias ; else 0
__global__ void k_pack_rec(const float* __restrict__ w_hh0, const float* __restrict__ w_ih0,
                           const float* __restrict__ b0,    const float* __restrict__ w_hh1,
                           unsigned short* __restrict__ wpack){
  int idx = blockIdx.x*256 + threadIdx.x;
  if (idx >= 3*WPACK_STRIDE) return;
  int dl = idx / WPACK_STRIDE;
  int r  = idx % WPACK_STRIDE;
  int j    = r & 7;
  int lane = (r >> 3) & 63;
  int kk   = (r >> 9) % 9;
  int nt   = (r / (9*512)) % 16;
  int w    = r / (16*9*512);
  int n = w*256 + nt*16 + (lane & 15);
  int k = kk*32 + ((lane >> 4) << 3) + j;
  float val = 0.f;
  if (dl < 2){
    if (k < 256)       val = w_hh0[(dl*G4 + n)*HID + k];
    else if (k < 260)  val = w_ih0[(dl*G4 + n)*4 + (k - 256)];
    else if (k == 260) val = b0[dl*G4 + n];
  } else {
    if (k < 256) val = w_hh1[n*HID + k];   // layer1 forward dir
  }
  wpack[idx] = f2bf(val);
}

__global__ void k_pack_wih1(const float* __restrict__ w, unsigned short* __restrict__ o, int n){
  int idx = blockIdx.x*256 + threadIdx.x;
  if (idx < n) o[idx] = f2bf(w[idx]);
}

// ---- recurrence: MODE 0 = layer0 (both dirs), MODE 1 = layer1 forward ----
// 256 threads = 4 waves; wave w owns gate cols [w*256,(w+1)*256); NB=16 batch rows/block
template<int MODE>
__global__ __launch_bounds__(256) void k_rec(
    const float* __restrict__ x,                // MODE0: [128][512][4]
    const unsigned short* __restrict__ wpack,
    const unsigned short* __restrict__ xp,      // MODE1: frag-packed bf16 gates
    unsigned short* __restrict__ y0,            // MODE0: bf16 [512][128][512]
    float* __restrict__ hS)                     // MODE1: fp32 [128][256] final h
{
  const int tid  = threadIdx.x;
  const int lane = tid & 63;
  const int w    = tid >> 6;
  int dir, bgrp;
  if (MODE == 0){ dir = blockIdx.x >> 3; bgrp = blockIdx.x & 7; }
  else          { dir = 0;               bgrp = blockIdx.x;     }
  const int b0 = bgrp * NB;
  constexpr int KK = (MODE == 0) ? 9 : 8;

  __shared__ __align__(16) unsigned short A_lds[16*288]; // h(256)|x(4)|1|pad, XOR-swizzled chunks
  __shared__ __align__(16) float g_lds[16*1028];         // gates, +4 pad per row

  const unsigned short* wp = wpack + ((MODE==0) ? dir*WPACK_STRIDE : 2*WPACK_STRIDE)
                                   + w*(16*9*512);

  for (int i = tid; i < 16*288; i += 256) A_lds[i] = 0;
  __syncthreads();
  if (MODE == 0 && tid < 16){
    A_lds[tid*288 + 260] = 0x3F80;  // 1.0 -> bias row
    int t0 = dir ? (T_LEN-1) : 0;
    const float* xr = &x[((size_t)(b0 + tid)*T_LEN + t0)*4];
    A_lds[tid*288 + 256] = f2bf(xr[0]);
    A_lds[tid*288 + 257] = f2bf(xr[1]);
    A_lds[tid*288 + 258] = f2bf(xr[2]);
    A_lds[tid*288 + 259] = f2bf(xr[3]);
  }
  float c_reg[16];
  #pragma unroll
  for (int i = 0; i < 16; ++i) c_reg[i] = 0.f;
  const int bb = tid >> 4;            // batch row for h-update
  const int j0 = (tid & 15) << 4;     // hidden slice base
  const int arow = lane & 15;
  __syncthreads();

  for (int tt = 0; tt < T_LEN; ++tt){
    const int t = (MODE == 0 && dir) ? (T_LEN-1-tt) : tt;

    // ---- A fragments (h | x | 1) from LDS, kept in regs for all 16 n-tiles ----
    bf16x8 a[KK];
    #pragma unroll
    for (int kk = 0; kk < KK; ++kk){
      int chunk = (kk < 8) ? ((kk*4 + (lane>>4)) ^ arow) : (32 + (lane>>4));
      a[kk] = *(const bf16x8*)&A_lds[arow*288 + chunk*8];
    }

    // ---- MFMA over 16 n-tiles, streaming B from L2; write D-frags to g_lds ----
    const int gcol = w*256 + (lane & 15);
    const int grow = (lane >> 4) * 4;
    const bf16x8* bpw = (const bf16x8*)wp;
    #pragma unroll 2
    for (int nt = 0; nt < 16; ++nt){
      f32x4 acc;
      if (MODE == 1){
        const unsigned short* xpp = xp + ((((size_t)t*8 + bgrp)*4 + w)*16 + nt)*256 + lane*4;
        acc[0] = bf2f(xpp[0]); acc[1] = bf2f(xpp[1]);
        acc[2] = bf2f(xpp[2]); acc[3] = bf2f(xpp[3]);
      } else {
        acc = (f32x4){0.f, 0.f, 0.f, 0.f};
      }
      const bf16x8* bp = bpw + (size_t)(nt*9)*64 + lane;
      #pragma unroll
      for (int kk = 0; kk < KK; ++kk)
        acc = __builtin_amdgcn_mfma_f32_16x16x32_bf16(a[kk], bp[kk*64], acc, 0, 0, 0);
      float* gp = &g_lds[grow*1028 + gcol + nt*16];
      gp[0] = acc[0]; gp[1028] = acc[1]; gp[2056] = acc[2]; gp[3084] = acc[3];
    }
    __syncthreads();

    // ---- h/c update: thread -> (batch bb, hidden j0..j0+15) ----
    {
      const float* gi = &g_lds[bb*1028 + j0];
      float hval[16];
      #pragma unroll
      for (int cc = 0; cc < 16; ++cc){
        float iv = gi[cc];
        float fv = gi[256 + cc];
        float gg = gi[512 + cc];
        float ov = gi[768 + cc];
        float c  = sigmf(fv)*c_reg[cc] + sigmf(iv)*tanhf_(gg);
        c_reg[cc] = c;
        hval[cc] = sigmf(ov)*tanhf_(c);
      }
      unsigned short hb[16];
      #pragma unroll
      for (int cc = 0; cc < 16; ++cc) hb[cc] = f2bf(hval[cc]);
      int cbase = (tid & 15) * 2;
      *(bf16x8*)&A_lds[bb*288 + ((cbase    ) ^ bb)*8] = *(bf16x8*)&hb[0];
      *(bf16x8*)&A_lds[bb*288 + ((cbase + 1) ^ bb)*8] = *(bf16x8*)&hb[8];

      if (MODE == 0){
        unsigned short* yp = &y0[((size_t)t*BATCH + (b0 + bb))*(2*HID) + dir*HID + j0];
        *(uint4*)yp       = *(uint4*)&hb[0];
        *(uint4*)(yp + 8) = *(uint4*)&hb[8];
        if (tid < 16){  // prefetch next x into A tail (tail frag already consumed)
          int tn = dir ? (t > 0 ? t-1 : 0) : (t < T_LEN-1 ? t+1 : t);
          const float* xr = &x[((size_t)(b0 + tid)*T_LEN + tn)*4];
          A_lds[tid*288 + 256] = f2bf(xr[0]);
          A_lds[tid*288 + 257] = f2bf(xr[1]);
          A_lds[tid*288 + 258] = f2bf(xr[2]);
          A_lds[tid*288 + 259] = f2bf(xr[3]);
        }
      } else if (tt == T_LEN-1){
        float* hp = &hS[(size_t)(b0 + bb)*HID + j0];
        #pragma unroll
        for (int cc = 0; cc < 16; ++cc) hp[cc] = hval[cc];
      }
    }
    __syncthreads();
  }
}

// ---- bf16 MFMA GEMM: C[M][1024] = A[M][512] * B[1024][512]^T + bias ----
// grid (8, M/128), 256 thr, 128x128 tile, BK=64. PLAIN=0: frag-packed bf16 out; PLAIN=1: fp32 [M][1024]
template<int PLAIN>
__global__ __launch_bounds__(256) void k_gemm_bf(
    const unsigned short* __restrict__ A, const unsigned short* __restrict__ B,
    const float* __restrict__ bias, unsigned short* __restrict__ outF, float* __restrict__ outP)
{
  __shared__ __align__(16) unsigned short As[128*64];
  __shared__ __align__(16) unsigned short Bs[128*64];
  const int tid  = threadIdx.x;
  const int lane = tid & 63;
  const int w = tid >> 6, wm = w >> 1, wn = w & 1;
  const int t  = blockIdx.y;
  const int n0 = blockIdx.x * 128;

  f32x4 acc[4][4];
  #pragma unroll
  for (int i = 0; i < 4; ++i)
    #pragma unroll
    for (int jx = 0; jx < 4; ++jx) acc[i][jx] = (f32x4){0.f,0.f,0.f,0.f};

  const int sr = tid >> 3;   // 0..31
  const int sq = tid & 7;    // chunk 0..7

  for (int k0 = 0; k0 < 512; k0 += 64){
    #pragma unroll
    for (int it = 0; it < 4; ++it){
      int r = sr + it*32;
      uint4 av = *(const uint4*)&A[((size_t)t*128 + r)*512 + k0 + sq*8];
      uint4 bv = *(const uint4*)&B[((size_t)(n0 + r))*512 + k0 + sq*8];
      *(uint4*)&As[r*64 + (sq ^ (r & 7))*8] = av;
      *(uint4*)&Bs[r*64 + (sq ^ (r & 7))*8] = bv;
    }
    __syncthreads();
    bf16x8 af[4][2], bfv[4][2];
    #pragma unroll
    for (int mt = 0; mt < 4; ++mt)
      #pragma unroll
      for (int kk = 0; kk < 2; ++kk){
        int row = wm*64 + mt*16 + (lane & 15);
        af[mt][kk] = *(const bf16x8*)&As[row*64 + ((kk*4 + (lane>>4)) ^ (row & 7))*8];
      }
    #pragma unroll
    for (int nl = 0; nl < 4; ++nl)
      #pragma unroll
      for (int kk = 0; kk < 2; ++kk){
        int row = wn*64 + nl*16 + (lane & 15);
        bfv[nl][kk] = *(const bf16x8*)&Bs[row*64 + ((kk*4 + (lane>>4)) ^ (row & 7))*8];
      }
    #pragma unroll
    for (int mt = 0; mt < 4; ++mt)
      #pragma unroll
      for (int nl = 0; nl < 4; ++nl){
        acc[mt][nl] = __builtin_amdgcn_mfma_f32_16x16x32_bf16(af[mt][0], bfv[nl][0], acc[mt][nl], 0,0,0);
        acc[mt][nl] = __builtin_amdgcn_mfma_f32_16x16x32_bf16(af[mt][1], bfv[nl][1], acc[mt][nl], 0,0,0);
      }
    __syncthreads();
  }

  #pragma unroll
  for (int mt = 0; mt < 4; ++mt){
    #pragma unroll
    for (int nl = 0; nl < 4; ++nl){
      int ng = n0 + wn*64 + nl*16 + (lane & 15);
      float bv = bias[ng];
      f32x4 v = acc[mt][nl];
      if (PLAIN){
        int mrow = wm*64 + mt*16 + (lane >> 4)*4;
        #pragma unroll
        for (int r = 0; r < 4; ++r)
          outP[((size_t)t*128 + mrow + r)*G4 + ng] = v[r] + bv;
      } else {
        int bgrp = wm*4 + mt;
        int wrec = ng >> 8;
        int nt   = (ng >> 4) & 15;
        unsigned short hb[4];
        #pragma unroll
        for (int r = 0; r < 4; ++r) hb[r] = f2bf(v[r] + bv);
        *(uint2*)&outF[((((size_t)t*8 + bgrp)*4 + wrec)*16 + nt)*256 + lane*4] = *(uint2*)hb;
      }
    }
  }
}

// ---- final: layer-1 bwd single step + combine + out proj + softmax ----
__global__ __launch_bounds__(256) void k_final(const float* __restrict__ hS,
                                               const float* __restrict__ xp1b,
                                               const float* __restrict__ w_out,
                                               const float* __restrict__ b_out,
                                               float* __restrict__ out)
{
  const int b = blockIdx.x, j = threadIdx.x;
  float iv = xp1b[b*G4 + 0*HID + j];
  float gv = xp1b[b*G4 + 2*HID + j];
  float ov = xp1b[b*G4 + 3*HID + j];
  float c  = sigmf(iv)*tanhf_(gv);
  float hb = sigmf(ov)*tanhf_(c);
  float last = hS[b*HID + j] + hb;

  __shared__ float part[3][256];
  part[0][j] = last * w_out[0*HID + j];
  part[1][j] = last * w_out[1*HID + j];
  part[2][j] = last * w_out[2*HID + j];
  __syncthreads();
  for (int s = 128; s > 0; s >>= 1){
    if (j < s){
      part[0][j] += part[0][j+s];
      part[1][j] += part[1][j+s];
      part[2][j] += part[2][j+s];
    }
    __syncthreads();
  }
  if (j == 0){
    float l0 = part[0][0] + b_out[0];
    float l1 = part[1][0] + b_out[1];
    float l2 = part[2][0] + b_out[2];
    float m = fmaxf(l0, fmaxf(l1, l2));
    float e0 = __expf(l0-m), e1 = __expf(l1-m), e2 = __expf(l2-m);
    float s = e0 + e1 + e2;
    out[b*3+0] = e0/s; out[b*3+1] = e1/s; out[b*3+2] = e2/s;
  }
}

extern "C" void kernel_launch(void* const* d_in, const int* in_sizes, int n_in,
                              void* d_out, int out_size, void* d_ws, size_t ws_size,
                              hipStream_t stream) {
  const float* x     = (const float*)d_in[0];
  const float* w_ih0 = (const float*)d_in[1];
  const float* w_hh0 = (const float*)d_in[2];
  const float* b0p   = (const float*)d_in[3];
  const float* w_ih1 = (const float*)d_in[4];
  const float* w_hh1 = (const float*)d_in[5];
  const float* b1p   = (const float*)d_in[6];
  const float* w_out = (const float*)d_in[7];
  const float* b_out = (const float*)d_in[8];
  float* out = (float*)d_out;

  // workspace layout
  unsigned short* y0    = (unsigned short*)d_ws;                    // 512*128*512 bf16
  unsigned short* xp1   = y0   + (size_t)T_LEN*BATCH*2*HID;         // 512*128*1024 bf16
  unsigned short* wpack = xp1  + (size_t)T_LEN*BATCH*G4;            // 3*294912 bf16
  unsigned short* wih1p = wpack + 3*WPACK_STRIDE;                   // 2*1024*512 bf16
  float*          xp1b  = (float*)(wih1p + 2*G4*2*HID);             // 128*1024 f32
  float*          hS    = xp1b + BATCH*G4;                          // 128*256 f32

  k_pack_rec<<<(3*WPACK_STRIDE + 255)/256, 256, 0, stream>>>(w_hh0, w_ih0, b0p, w_hh1, wpack);
  k_pack_wih1<<<(2*G4*2*HID + 255)/256, 256, 0, stream>>>(w_ih1, wih1p, 2*G4*2*HID);

  // layer 0, both directions
  k_rec<0><<<16, 256, 0, stream>>>(x, wpack, nullptr, y0, nullptr);

  // layer-1 input projection (fwd dir), frag-packed bf16 out
  k_gemm_bf<0><<<dim3(8, 512), 256, 0, stream>>>(y0, wih1p, b1p, xp1, nullptr);

  // layer-1 backward first step gates: y0[511] @ w_ih1_bwd^T + b1_bwd, plain fp32
  k_gemm_bf<1><<<dim3(8, 1), 256, 0, stream>>>(y0 + (size_t)(T_LEN-1)*BATCH*2*HID,
                                               wih1p + (size_t)G4*2*HID, b1p + G4,
                                               nullptr, xp1b);

  // layer 1 forward recurrence
  k_rec<1><<<8, 256, 0, stream>>>(nullptr, wpack, xp1, nullptr, hS);

  k_final<<<BATCH, 256, 0, stream>>>(hS, xp1b, w_out, b_out, out);
}

// Round 3
// 7226.329 us; speedup vs baseline: 2.4345x; 1.4249x over previous
//
#include <hip/hip_runtime.h>

typedef __attribute__((ext_vector_type(8))) short bf16x8;
typedef __attribute__((ext_vector_type(4))) float f32x4;

#define T_LEN 512
#define BATCH 128
#define HID   256
#define G4    1024
#define NB    16
#define WPACK_STRIDE (16*4*9*64*8)   // 294912 bf16 per dir-layer

__device__ __forceinline__ float sigmf(float x){ return 1.0f/(1.0f + __expf(-x)); }
__device__ __forceinline__ float tanhf_(float x){ return 1.0f - 2.0f/(1.0f + __expf(2.0f*x)); }

__device__ __forceinline__ unsigned short f2bf(float f){
  union{float f;unsigned u;} v; v.f=f;
  unsigned r = v.u + 0x7FFF + ((v.u>>16)&1);
  return (unsigned short)(r>>16);
}
__device__ __forceinline__ float bf2f(unsigned short b){
  union{unsigned u;float f;} v; v.u = ((unsigned)b)<<16; return v.f;
}

// ---- pack recurrent weights into per-wave B-fragment stream order ----
// wpack[dl][w:16][g:4][kk:9][lane:64][j:8]
// B[k][n]: n = g*256 + w*16 + (lane&15), k = kk*32 + (lane>>4)*8 + j
// layer0 (dl<2): k<256 -> w_hh ; 256..259 -> w_ih ; 260 -> bias ; else 0
__global__ void k_pack_rec(const float* __restrict__ w_hh0, const float* __restrict__ w_ih0,
                           const float* __restrict__ b0,    const float* __restrict__ w_hh1,
                           unsigned short* __restrict__ wpack){
  int idx = blockIdx.x*256 + threadIdx.x;
  if (idx >= 3*WPACK_STRIDE) return;
  int dl = idx / WPACK_STRIDE;
  int r  = idx % WPACK_STRIDE;
  int j    = r & 7;
  int lane = (r >> 3) & 63;
  int kk   = (r >> 9) % 9;
  int g    = (r / (9*512)) % 4;
  int w    = r / (4*9*512);
  int n = g*256 + w*16 + (lane & 15);
  int k = kk*32 + ((lane >> 4) << 3) + j;
  float val = 0.f;
  if (dl < 2){
    if (k < 256)       val = w_hh0[(dl*G4 + n)*HID + k];
    else if (k < 260)  val = w_ih0[(dl*G4 + n)*4 + (k - 256)];
    else if (k == 260) val = b0[dl*G4 + n];
  } else {
    if (k < 256) val = w_hh1[n*HID + k];   // layer1 forward dir
  }
  wpack[idx] = f2bf(val);
}

__global__ void k_pack_wih1(const float* __restrict__ w, unsigned short* __restrict__ o, int n){
  int idx = blockIdx.x*256 + threadIdx.x;
  if (idx < n) o[idx] = f2bf(w[idx]);
}

// ---- recurrence: MODE 0 = layer0 (both dirs), MODE 1 = layer1 forward ----
// 1024 threads = 16 waves (4/SIMD). Wave w owns hidden cols [w*16,w*16+16) for
// ALL 4 gate types -> gates for (batch,j) stay in-lane; c in registers; one
// barrier/step; h -> double-buffered A_lds (bf16).
template<int MODE>
__global__ __launch_bounds__(1024) void k_rec(
    const float* __restrict__ x,                // MODE0: [128][512][4]
    const unsigned short* __restrict__ wpack,
    const unsigned short* __restrict__ xp,      // MODE1: frag-packed bf16 gates
    unsigned short* __restrict__ y0,            // MODE0: bf16 [512][128][512]
    float* __restrict__ hS)                     // MODE1: fp32 [128][256] final h
{
  const int tid  = threadIdx.x;
  const int lane = tid & 63;
  const int w    = tid >> 6;
  int dir, bgrp;
  if (MODE == 0){ dir = blockIdx.x >> 3; bgrp = blockIdx.x & 7; }
  else          { dir = 0;               bgrp = blockIdx.x;     }
  const int b0 = bgrp * NB;
  constexpr int KK = (MODE == 0) ? 9 : 8;

  // [buf][row:16][288 u16]  row stride 288 u16 = 576B (144 dwords == 16 mod 32
  // -> 16 rows spread over 2 bank-halves; no extra swizzle needed)
  __shared__ __align__(16) unsigned short A_lds[2][16*288];

  const unsigned short* wp = wpack + ((MODE==0) ? dir*WPACK_STRIDE : 2*WPACK_STRIDE)
                                   + w*(4*9*512);
  const bf16x8* bwave = (const bf16x8*)wp;

  for (int i = tid; i < 2*16*288; i += 1024) ((unsigned short*)A_lds)[i] = 0;
  __syncthreads();
  if (MODE == 0 && tid < 16){
    A_lds[0][tid*288 + 260] = 0x3F80;  // 1.0 -> bias row (both buffers)
    A_lds[1][tid*288 + 260] = 0x3F80;
    int t0 = dir ? (T_LEN-1) : 0;
    const float* xr = &x[((size_t)(b0 + tid)*T_LEN + t0)*4];
    A_lds[0][tid*288 + 256] = f2bf(xr[0]);
    A_lds[0][tid*288 + 257] = f2bf(xr[1]);
    A_lds[0][tid*288 + 258] = f2bf(xr[2]);
    A_lds[0][tid*288 + 259] = f2bf(xr[3]);
  }

  float c_reg[4];
  #pragma unroll
  for (int i = 0; i < 4; ++i) c_reg[i] = 0.f;

  const int arow = lane & 15;          // A-frag row this lane reads
  const int jcol = w*16 + (lane & 15); // hidden col this lane owns
  const int rb   = (lane >> 4) * 4;    // batch-row base this lane owns

  for (int tt = 0; tt < T_LEN; ++tt){
    const int t = (MODE == 0 && dir) ? (T_LEN-1-tt) : tt;
    const unsigned short* Acur = A_lds[tt & 1];
    unsigned short* Anxt = (unsigned short*)A_lds[(tt + 1) & 1];

    __syncthreads();   // h(t)/x(t) complete in Acur

    // C-in (MODE1): 4 x uint2 early loads
    uint2 cin[4];
    if (MODE == 1){
      #pragma unroll
      for (int g = 0; g < 4; ++g)
        cin[g] = *(const uint2*)(xp + (((((size_t)t*8 + bgrp)*16 + w)*4 + g)*64 + lane)*4);
    }

    // A fragments (h | x | 1), shared by all 4 gate tiles
    bf16x8 a[KK];
    #pragma unroll
    for (int kk = 0; kk < KK; ++kk)
      a[kk] = *(const bf16x8*)&Acur[arow*288 + kk*32 + (lane>>4)*8];

    // 4 gate tiles x KK MFMA, B streamed from L2
    f32x4 acc[4];
    #pragma unroll
    for (int g = 0; g < 4; ++g){
      if (MODE == 1){
        unsigned short c0 = (unsigned short)(cin[g].x & 0xFFFF);
        unsigned short c1 = (unsigned short)(cin[g].x >> 16);
        unsigned short c2 = (unsigned short)(cin[g].y & 0xFFFF);
        unsigned short c3 = (unsigned short)(cin[g].y >> 16);
        acc[g] = (f32x4){bf2f(c0), bf2f(c1), bf2f(c2), bf2f(c3)};
      } else {
        acc[g] = (f32x4){0.f, 0.f, 0.f, 0.f};
      }
      const bf16x8* bp = bwave + (size_t)g*9*64 + lane;
      #pragma unroll
      for (int kk = 0; kk < KK; ++kk)
        acc[g] = __builtin_amdgcn_mfma_f32_16x16x32_bf16(a[kk], bp[kk*64], acc[g], 0, 0, 0);
    }

    // elementwise h/c update, all in-register; write h(t+1) to Anxt
    #pragma unroll
    for (int r = 0; r < 4; ++r){
      float iv = acc[0][r], fv = acc[1][r], gg = acc[2][r], ov = acc[3][r];
      float c  = sigmf(fv)*c_reg[r] + sigmf(iv)*tanhf_(gg);
      c_reg[r] = c;
      float h  = sigmf(ov)*tanhf_(c);
      unsigned short hb = f2bf(h);
      int br = rb + r;
      Anxt[br*288 + jcol] = hb;
      if (MODE == 0){
        y0[((size_t)t*BATCH + (b0 + br))*(2*HID) + dir*HID + jcol] = hb;
      } else if (tt == T_LEN-1){
        hS[(size_t)(b0 + br)*HID + jcol] = h;
      }
    }

    if (MODE == 0 && tid < 16){  // prefetch next x into Anxt tail
      int tn = dir ? (t > 0 ? t-1 : 0) : (t < T_LEN-1 ? t+1 : t);
      const float* xr = &x[((size_t)(b0 + tid)*T_LEN + tn)*4];
      Anxt[tid*288 + 256] = f2bf(xr[0]);
      Anxt[tid*288 + 257] = f2bf(xr[1]);
      Anxt[tid*288 + 258] = f2bf(xr[2]);
      Anxt[tid*288 + 259] = f2bf(xr[3]);
    }
  }
}

// ---- bf16 MFMA GEMM: C[M][1024] = A[M][512] * B[1024][512]^T + bias ----
// grid (8, M/128), 256 thr, 128x128 tile, BK=64. PLAIN=0: frag-packed bf16 out; PLAIN=1: fp32 [M][1024]
template<int PLAIN>
__global__ __launch_bounds__(256) void k_gemm_bf(
    const unsigned short* __restrict__ A, const unsigned short* __restrict__ B,
    const float* __restrict__ bias, unsigned short* __restrict__ outF, float* __restrict__ outP)
{
  __shared__ __align__(16) unsigned short As[128*64];
  __shared__ __align__(16) unsigned short Bs[128*64];
  const int tid  = threadIdx.x;
  const int lane = tid & 63;
  const int w = tid >> 6, wm = w >> 1, wn = w & 1;
  const int t  = blockIdx.y;
  const int n0 = blockIdx.x * 128;

  f32x4 acc[4][4];
  #pragma unroll
  for (int i = 0; i < 4; ++i)
    #pragma unroll
    for (int jx = 0; jx < 4; ++jx) acc[i][jx] = (f32x4){0.f,0.f,0.f,0.f};

  const int sr = tid >> 3;   // 0..31
  const int sq = tid & 7;    // chunk 0..7

  for (int k0 = 0; k0 < 512; k0 += 64){
    #pragma unroll
    for (int it = 0; it < 4; ++it){
      int r = sr + it*32;
      uint4 av = *(const uint4*)&A[((size_t)t*128 + r)*512 + k0 + sq*8];
      uint4 bv = *(const uint4*)&B[((size_t)(n0 + r))*512 + k0 + sq*8];
      *(uint4*)&As[r*64 + (sq ^ (r & 7))*8] = av;
      *(uint4*)&Bs[r*64 + (sq ^ (r & 7))*8] = bv;
    }
    __syncthreads();
    bf16x8 af[4][2], bfv[4][2];
    #pragma unroll
    for (int mt = 0; mt < 4; ++mt)
      #pragma unroll
      for (int kk = 0; kk < 2; ++kk){
        int row = wm*64 + mt*16 + (lane & 15);
        af[mt][kk] = *(const bf16x8*)&As[row*64 + ((kk*4 + (lane>>4)) ^ (row & 7))*8];
      }
    #pragma unroll
    for (int nl = 0; nl < 4; ++nl)
      #pragma unroll
      for (int kk = 0; kk < 2; ++kk){
        int row = wn*64 + nl*16 + (lane & 15);
        bfv[nl][kk] = *(const bf16x8*)&Bs[row*64 + ((kk*4 + (lane>>4)) ^ (row & 7))*8];
      }
    #pragma unroll
    for (int mt = 0; mt < 4; ++mt)
      #pragma unroll
      for (int nl = 0; nl < 4; ++nl){
        acc[mt][nl] = __builtin_amdgcn_mfma_f32_16x16x32_bf16(af[mt][0], bfv[nl][0], acc[mt][nl], 0,0,0);
        acc[mt][nl] = __builtin_amdgcn_mfma_f32_16x16x32_bf16(af[mt][1], bfv[nl][1], acc[mt][nl], 0,0,0);
      }
    __syncthreads();
  }

  #pragma unroll
  for (int mt = 0; mt < 4; ++mt){
    #pragma unroll
    for (int nl = 0; nl < 4; ++nl){
      int ng = n0 + wn*64 + nl*16 + (lane & 15);
      float bv = bias[ng];
      f32x4 v = acc[mt][nl];
      if (PLAIN){
        int mrow = wm*64 + mt*16 + (lane >> 4)*4;
        #pragma unroll
        for (int r = 0; r < 4; ++r)
          outP[((size_t)t*128 + mrow + r)*G4 + ng] = v[r] + bv;
      } else {
        // frag-pack for k_rec<1>: [t][bgrp:8][w:16][g:4][lane:64][r:4]
        int bgrp = wm*4 + mt;
        int wrec = (ng >> 4) & 15;
        int g    = ng >> 8;
        unsigned short hb[4];
        #pragma unroll
        for (int r = 0; r < 4; ++r) hb[r] = f2bf(v[r] + bv);
        *(uint2*)&outF[(((((size_t)t*8 + bgrp)*16 + wrec)*4 + g)*64 + lane)*4] = *(uint2*)hb;
      }
    }
  }
}

// ---- final: layer-1 bwd single step + combine + out proj + softmax ----
__global__ __launch_bounds__(256) void k_final(const float* __restrict__ hS,
                                               const float* __restrict__ xp1b,
                                               const float* __restrict__ w_out,
                                               const float* __restrict__ b_out,
                                               float* __restrict__ out)
{
  const int b = blockIdx.x, j = threadIdx.x;
  float iv = xp1b[b*G4 + 0*HID + j];
  float gv = xp1b[b*G4 + 2*HID + j];
  float ov = xp1b[b*G4 + 3*HID + j];
  float c  = sigmf(iv)*tanhf_(gv);
  float hb = sigmf(ov)*tanhf_(c);
  float last = hS[b*HID + j] + hb;

  __shared__ float part[3][256];
  part[0][j] = last * w_out[0*HID + j];
  part[1][j] = last * w_out[1*HID + j];
  part[2][j] = last * w_out[2*HID + j];
  __syncthreads();
  for (int s = 128; s > 0; s >>= 1){
    if (j < s){
      part[0][j] += part[0][j+s];
      part[1][j] += part[1][j+s];
      part[2][j] += part[2][j+s];
    }
    __syncthreads();
  }
  if (j == 0){
    float l0 = part[0][0] + b_out[0];
    float l1 = part[1][0] + b_out[1];
    float l2 = part[2][0] + b_out[2];
    float m = fmaxf(l0, fmaxf(l1, l2));
    float e0 = __expf(l0-m), e1 = __expf(l1-m), e2 = __expf(l2-m);
    float s = e0 + e1 + e2;
    out[b*3+0] = e0/s; out[b*3+1] = e1/s; out[b*3+2] = e2/s;
  }
}

extern "C" void kernel_launch(void* const* d_in, const int* in_sizes, int n_in,
                              void* d_out, int out_size, void* d_ws, size_t ws_size,
                              hipStream_t stream) {
  const float* x     = (const float*)d_in[0];
  const float* w_ih0 = (const float*)d_in[1];
  const float* w_hh0 = (const float*)d_in[2];
  const float* b0p   = (const float*)d_in[3];
  const float* w_ih1 = (const float*)d_in[4];
  const float* w_hh1 = (const float*)d_in[5];
  const float* b1p   = (const float*)d_in[6];
  const float* w_out = (const float*)d_in[7];
  const float* b_out = (const float*)d_in[8];
  float* out = (float*)d_out;

  // workspace layout
  unsigned short* y0    = (unsigned short*)d_ws;                    // 512*128*512 bf16
  unsigned short* xp1   = y0   + (size_t)T_LEN*BATCH*2*HID;         // 512*128*1024 bf16
  unsigned short* wpack = xp1  + (size_t)T_LEN*BATCH*G4;            // 3*294912 bf16
  unsigned short* wih1p = wpack + 3*WPACK_STRIDE;                   // 2*1024*512 bf16
  float*          xp1b  = (float*)(wih1p + 2*G4*2*HID);             // 128*1024 f32
  float*          hS    = xp1b + BATCH*G4;                          // 128*256 f32

  k_pack_rec<<<(3*WPACK_STRIDE + 255)/256, 256, 0, stream>>>(w_hh0, w_ih0, b0p, w_hh1, wpack);
  k_pack_wih1<<<(2*G4*2*HID + 255)/256, 256, 0, stream>>>(w_ih1, wih1p, 2*G4*2*HID);

  // layer 0, both directions
  k_rec<0><<<16, 1024, 0, stream>>>(x, wpack, nullptr, y0, nullptr);

  // layer-1 input projection (fwd dir), frag-packed bf16 out
  k_gemm_bf<0><<<dim3(8, 512), 256, 0, stream>>>(y0, wih1p, b1p, xp1, nullptr);

  // layer-1 backward first step gates: y0[511] @ w_ih1_bwd^T + b1_bwd, plain fp32
  k_gemm_bf<1><<<dim3(8, 1), 256, 0, stream>>>(y0 + (size_t)(T_LEN-1)*BATCH*2*HID,
                                               wih1p + (size_t)G4*2*HID, b1p + G4,
                                               nullptr, xp1b);

  // layer 1 forward recurrence
  k_rec<1><<<8, 1024, 0, stream>>>(nullptr, wpack, xp1, nullptr, hS);

  k_final<<<BATCH, 256, 0, stream>>>(hS, xp1b, w_out, b_out, out);
}

// Round 4
// 5503.030 us; speedup vs baseline: 3.1969x; 1.3132x over previous
//
#include <hip/hip_runtime.h>

typedef __attribute__((ext_vector_type(8))) short bf16x8;
typedef __attribute__((ext_vector_type(4))) float f32x4;

#define T_LEN 512
#define BATCH 128
#define HID   256
#define G4    1024
#define WPACK_STRIDE (16*4*9*64*8)   // 294912 bf16 per dir-layer

__device__ __forceinline__ float sigmf(float x){ return 1.0f/(1.0f + __expf(-x)); }
__device__ __forceinline__ float tanhf_(float x){ return 1.0f - 2.0f/(1.0f + __expf(2.0f*x)); }

__device__ __forceinline__ unsigned short f2bf(float f){
  union{float f;unsigned u;} v; v.f=f;
  unsigned r = v.u + 0x7FFF + ((v.u>>16)&1);
  return (unsigned short)(r>>16);
}
__device__ __forceinline__ float bf2f(unsigned short b){
  union{unsigned u;float f;} v; v.u = ((unsigned)b)<<16; return v.f;
}

// ---- pack recurrent weights into per-wave B-fragment stream order ----
// wpack[dl][w16:16][g:4][kk:9][lane:64][j:8]
// B[k][n]: n = g*256 + w16*16 + (lane&15), k = kk*32 + (lane>>4)*8 + j
__global__ void k_pack_rec(const float* __restrict__ w_hh0, const float* __restrict__ w_ih0,
                           const float* __restrict__ b0,    const float* __restrict__ w_hh1,
                           unsigned short* __restrict__ wpack){
  int idx = blockIdx.x*256 + threadIdx.x;
  if (idx >= 3*WPACK_STRIDE) return;
  int dl = idx / WPACK_STRIDE;
  int r  = idx % WPACK_STRIDE;
  int j    = r & 7;
  int lane = (r >> 3) & 63;
  int kk   = (r >> 9) % 9;
  int g    = (r / (9*512)) % 4;
  int w    = r / (4*9*512);
  int n = g*256 + w*16 + (lane & 15);
  int k = kk*32 + ((lane >> 4) << 3) + j;
  float val = 0.f;
  if (dl < 2){
    if (k < 256)       val = w_hh0[(dl*G4 + n)*HID + k];
    else if (k < 260)  val = w_ih0[(dl*G4 + n)*4 + (k - 256)];
    else if (k == 260) val = b0[dl*G4 + n];
  } else {
    if (k < 256) val = w_hh1[n*HID + k];
  }
  wpack[idx] = f2bf(val);
}

__global__ void k_pack_wih1(const float* __restrict__ w, unsigned short* __restrict__ o, int n){
  int idx = blockIdx.x*256 + threadIdx.x;
  if (idx < n) o[idx] = f2bf(w[idx]);
}

// ---- recurrence, column-split x2 with register-resident weights ----
// MODE 0: layer0 both dirs, 32 blocks = (dir,bgrp,cb). MODE 1: layer1 fwd, 16 blocks.
// Block = 256 thr = 4 waves (1/SIMD). Wave holds B for 2 w16-slices x 4 gates
// in registers (never re-read). Per step the 2 blocks of a group exchange
// 16x128 bf16 h-halves via agent-scope atomics (bypass stale L2).
template<int MODE>
__global__ __launch_bounds__(256, 1) void k_rec(
    const float* __restrict__ x,
    const unsigned short* __restrict__ wpack,
    const unsigned short* __restrict__ xp,
    unsigned short* __restrict__ y0,
    float* __restrict__ hS,
    unsigned* __restrict__ cnt,               // per-group monotonic flag
    unsigned short* __restrict__ hx)          // per-group [16][256] bf16 exchange
{
  const int tid  = threadIdx.x;
  const int lane = tid & 63;
  const int w    = tid >> 6;                  // wave 0..3
  const int bx   = blockIdx.x;
  const int cb   = bx & 1;                    // column half
  int dir, bgrp, grp;
  if (MODE == 0){ grp = bx >> 1; dir = grp >> 3; bgrp = grp & 7; }
  else          { grp = bx >> 1; dir = 0;        bgrp = grp;     }
  const int b0 = bgrp * 16;
  constexpr int KK = (MODE == 0) ? 9 : 8;
  const int wbase16 = cb*8 + w*2;             // first of this wave's 2 w16-slices

  __shared__ __align__(16) unsigned short A_lds[2][16*288];

  // ---- load this wave's B slice into registers, once ----
  const bf16x8* bw = (const bf16x8*)(wpack
      + ((MODE==0) ? dir*WPACK_STRIDE : 2*WPACK_STRIDE)
      + (size_t)wbase16*(4*9*512));
  bf16x8 breg[2][4][KK];
  #pragma unroll
  for (int p = 0; p < 2; ++p)
    #pragma unroll
    for (int g = 0; g < 4; ++g)
      #pragma unroll
      for (int kk = 0; kk < KK; ++kk)
        breg[p][g][kk] = bw[((p*4 + g)*9 + kk)*64 + lane];

  for (int i = tid; i < 2*16*288; i += 256) ((unsigned short*)A_lds)[i] = 0;
  __syncthreads();
  if (MODE == 0 && tid < 16){
    A_lds[0][tid*288 + 260] = 0x3F80;
    A_lds[1][tid*288 + 260] = 0x3F80;
    int t0 = dir ? (T_LEN-1) : 0;
    const float* xr = &x[((size_t)(b0 + tid)*T_LEN + t0)*4];
    A_lds[0][tid*288 + 256] = f2bf(xr[0]);
    A_lds[0][tid*288 + 257] = f2bf(xr[1]);
    A_lds[0][tid*288 + 258] = f2bf(xr[2]);
    A_lds[0][tid*288 + 259] = f2bf(xr[3]);
  }

  float c_reg[2][4];
  #pragma unroll
  for (int p = 0; p < 2; ++p)
    #pragma unroll
    for (int r = 0; r < 4; ++r) c_reg[p][r] = 0.f;

  const int arow = lane & 15;
  const int rb   = (lane >> 4) * 4;
  int jcol[2];
  jcol[0] = wbase16*16 + (lane & 15);
  jcol[1] = jcol[0] + 16;

  // MODE1 C-in prefetch (double-buffered regs)
  uint2 cinC[2][4], cinN[2][4];
  if (MODE == 1){
    #pragma unroll
    for (int p = 0; p < 2; ++p)
      #pragma unroll
      for (int g = 0; g < 4; ++g)
        cinC[p][g] = *(const uint2*)(xp +
          ((((size_t)0*8 + bgrp)*16 + (wbase16+p))*4 + g)*256 + lane*4);
  }

  unsigned* hxw = (unsigned*)hx;
  const int pcb = cb ^ 1;

  for (int tt = 0; tt < T_LEN; ++tt){
    const int t = (MODE == 0 && dir) ? (T_LEN-1-tt) : tt;
    const unsigned short* Acur = A_lds[tt & 1];
    unsigned short* Anxt = (unsigned short*)A_lds[(tt + 1) & 1];

    __syncthreads();   // Acur fully assembled (own ds-writes + partner copy)

    // A fragments
    bf16x8 a[KK];
    #pragma unroll
    for (int kk = 0; kk < KK; ++kk)
      a[kk] = *(const bf16x8*)&Acur[arow*288 + kk*32 + (lane>>4)*8];

    // init acc, then issue next-step C-in loads (latency hidden under MFMA)
    f32x4 acc[2][4];
    #pragma unroll
    for (int p = 0; p < 2; ++p)
      #pragma unroll
      for (int g = 0; g < 4; ++g){
        if (MODE == 1){
          uint2 cv = cinC[p][g];
          acc[p][g] = (f32x4){bf2f((unsigned short)(cv.x & 0xFFFF)),
                              bf2f((unsigned short)(cv.x >> 16)),
                              bf2f((unsigned short)(cv.y & 0xFFFF)),
                              bf2f((unsigned short)(cv.y >> 16))};
        } else {
          acc[p][g] = (f32x4){0.f, 0.f, 0.f, 0.f};
        }
      }
    if (MODE == 1){
      int tn = (t + 1 < T_LEN) ? t + 1 : t;
      #pragma unroll
      for (int p = 0; p < 2; ++p)
        #pragma unroll
        for (int g = 0; g < 4; ++g)
          cinN[p][g] = *(const uint2*)(xp +
            ((((size_t)tn*8 + bgrp)*16 + (wbase16+p))*4 + g)*256 + lane*4);
    }

    // MFMA: B entirely from registers
    #pragma unroll
    for (int p = 0; p < 2; ++p)
      #pragma unroll
      for (int g = 0; g < 4; ++g)
        #pragma unroll
        for (int kk = 0; kk < KK; ++kk)
          acc[p][g] = __builtin_amdgcn_mfma_f32_16x16x32_bf16(a[kk], breg[p][g][kk], acc[p][g], 0, 0, 0);

    // elementwise h/c update; own h -> Anxt LDS + hx (agent-coherent stores)
    #pragma unroll
    for (int p = 0; p < 2; ++p){
      #pragma unroll
      for (int r = 0; r < 4; ++r){
        float iv = acc[p][0][r], fv = acc[p][1][r], gg = acc[p][2][r], ov = acc[p][3][r];
        float c  = sigmf(fv)*c_reg[p][r] + sigmf(iv)*tanhf_(gg);
        c_reg[p][r] = c;
        float h  = sigmf(ov)*tanhf_(c);
        unsigned short hb = f2bf(h);
        int br = rb + r;
        Anxt[br*288 + jcol[p]] = hb;
        if (tt < T_LEN-1)
          __hip_atomic_store(&hx[grp*4096 + br*256 + jcol[p]], (short)hb,
                             __ATOMIC_RELAXED, __HIP_MEMORY_SCOPE_AGENT);
        if (MODE == 0){
          y0[((size_t)t*BATCH + (b0 + br))*(2*HID) + dir*HID + jcol[p]] = hb;
        } else if (tt == T_LEN-1){
          hS[(size_t)(b0 + br)*HID + jcol[p]] = h;
        }
      }
    }

    if (MODE == 0 && tid < 16){  // next x into Anxt tail
      int tn = dir ? (t > 0 ? t-1 : 0) : (t < T_LEN-1 ? t+1 : t);
      const float* xr = &x[((size_t)(b0 + tid)*T_LEN + tn)*4];
      Anxt[tid*288 + 256] = f2bf(xr[0]);
      Anxt[tid*288 + 257] = f2bf(xr[1]);
      Anxt[tid*288 + 258] = f2bf(xr[2]);
      Anxt[tid*288 + 259] = f2bf(xr[3]);
    }

    if (MODE == 1){
      #pragma unroll
      for (int p = 0; p < 2; ++p)
        #pragma unroll
        for (int g = 0; g < 4; ++g) cinC[p][g] = cinN[p][g];
    }

    if (tt < T_LEN-1){
      __syncthreads();   // all waves' hx stores issued
      if (tid == 0){
        __hip_atomic_fetch_add(&cnt[grp], 1u, __ATOMIC_RELEASE, __HIP_MEMORY_SCOPE_AGENT);
        unsigned tgt = 2u*(tt+1);
        while (__hip_atomic_load(&cnt[grp], __ATOMIC_RELAXED, __HIP_MEMORY_SCOPE_AGENT) < tgt){}
        (void)__hip_atomic_load(&cnt[grp], __ATOMIC_ACQUIRE, __HIP_MEMORY_SCOPE_AGENT);
      }
      __syncthreads();
      // copy partner half into Anxt (agent-scope loads bypass stale cache)
      #pragma unroll
      for (int rep = 0; rep < 4; ++rep){
        int li = tid + rep*256;
        int row = li >> 6, c32 = li & 63;
        unsigned v = __hip_atomic_load(&hxw[grp*2048 + row*128 + pcb*64 + c32],
                                       __ATOMIC_RELAXED, __HIP_MEMORY_SCOPE_AGENT);
        *(unsigned*)&Anxt[row*288 + pcb*128 + c32*2] = v;
      }
    }
  }
}

// ---- bf16 MFMA GEMM: C[M][1024] = A[M][512] * B[1024][512]^T + bias ----
template<int PLAIN>
__global__ __launch_bounds__(256) void k_gemm_bf(
    const unsigned short* __restrict__ A, const unsigned short* __restrict__ B,
    const float* __restrict__ bias, unsigned short* __restrict__ outF, float* __restrict__ outP)
{
  __shared__ __align__(16) unsigned short As[128*64];
  __shared__ __align__(16) unsigned short Bs[128*64];
  const int tid  = threadIdx.x;
  const int lane = tid & 63;
  const int w = tid >> 6, wm = w >> 1, wn = w & 1;
  const int t  = blockIdx.y;
  const int n0 = blockIdx.x * 128;

  f32x4 acc[4][4];
  #pragma unroll
  for (int i = 0; i < 4; ++i)
    #pragma unroll
    for (int jx = 0; jx < 4; ++jx) acc[i][jx] = (f32x4){0.f,0.f,0.f,0.f};

  const int sr = tid >> 3;
  const int sq = tid & 7;

  for (int k0 = 0; k0 < 512; k0 += 64){
    #pragma unroll
    for (int it = 0; it < 4; ++it){
      int r = sr + it*32;
      uint4 av = *(const uint4*)&A[((size_t)t*128 + r)*512 + k0 + sq*8];
      uint4 bv = *(const uint4*)&B[((size_t)(n0 + r))*512 + k0 + sq*8];
      *(uint4*)&As[r*64 + (sq ^ (r & 7))*8] = av;
      *(uint4*)&Bs[r*64 + (sq ^ (r & 7))*8] = bv;
    }
    __syncthreads();
    bf16x8 af[4][2], bfv[4][2];
    #pragma unroll
    for (int mt = 0; mt < 4; ++mt)
      #pragma unroll
      for (int kk = 0; kk < 2; ++kk){
        int row = wm*64 + mt*16 + (lane & 15);
        af[mt][kk] = *(const bf16x8*)&As[row*64 + ((kk*4 + (lane>>4)) ^ (row & 7))*8];
      }
    #pragma unroll
    for (int nl = 0; nl < 4; ++nl)
      #pragma unroll
      for (int kk = 0; kk < 2; ++kk){
        int row = wn*64 + nl*16 + (lane & 15);
        bfv[nl][kk] = *(const bf16x8*)&Bs[row*64 + ((kk*4 + (lane>>4)) ^ (row & 7))*8];
      }
    #pragma unroll
    for (int mt = 0; mt < 4; ++mt)
      #pragma unroll
      for (int nl = 0; nl < 4; ++nl){
        acc[mt][nl] = __builtin_amdgcn_mfma_f32_16x16x32_bf16(af[mt][0], bfv[nl][0], acc[mt][nl], 0,0,0);
        acc[mt][nl] = __builtin_amdgcn_mfma_f32_16x16x32_bf16(af[mt][1], bfv[nl][1], acc[mt][nl], 0,0,0);
      }
    __syncthreads();
  }

  #pragma unroll
  for (int mt = 0; mt < 4; ++mt){
    #pragma unroll
    for (int nl = 0; nl < 4; ++nl){
      int ng = n0 + wn*64 + nl*16 + (lane & 15);
      float bv = bias[ng];
      f32x4 v = acc[mt][nl];
      if (PLAIN){
        int mrow = wm*64 + mt*16 + (lane >> 4)*4;
        #pragma unroll
        for (int r = 0; r < 4; ++r)
          outP[((size_t)t*128 + mrow + r)*G4 + ng] = v[r] + bv;
      } else {
        // frag-pack for k_rec<1>: [t][bgrp:8][w16:16][g:4][lane:64][r:4]
        int bgrp = wm*4 + mt;
        int wrec = (ng >> 4) & 15;
        int g    = ng >> 8;
        unsigned short hb[4];
        #pragma unroll
        for (int r = 0; r < 4; ++r) hb[r] = f2bf(v[r] + bv);
        *(uint2*)&outF[(((((size_t)t*8 + bgrp)*16 + wrec)*4 + g)*64 + lane)*4] = *(uint2*)hb;
      }
    }
  }
}

// ---- final: layer-1 bwd single step + combine + out proj + softmax ----
__global__ __launch_bounds__(256) void k_final(const float* __restrict__ hS,
                                               const float* __restrict__ xp1b,
                                               const float* __restrict__ w_out,
                                               const float* __restrict__ b_out,
                                               float* __restrict__ out)
{
  const int b = blockIdx.x, j = threadIdx.x;
  float iv = xp1b[b*G4 + 0*HID + j];
  float gv = xp1b[b*G4 + 2*HID + j];
  float ov = xp1b[b*G4 + 3*HID + j];
  float c  = sigmf(iv)*tanhf_(gv);
  float hb = sigmf(ov)*tanhf_(c);
  float last = hS[b*HID + j] + hb;

  __shared__ float part[3][256];
  part[0][j] = last * w_out[0*HID + j];
  part[1][j] = last * w_out[1*HID + j];
  part[2][j] = last * w_out[2*HID + j];
  __syncthreads();
  for (int s = 128; s > 0; s >>= 1){
    if (j < s){
      part[0][j] += part[0][j+s];
      part[1][j] += part[1][j+s];
      part[2][j] += part[2][j+s];
    }
    __syncthreads();
  }
  if (j == 0){
    float l0 = part[0][0] + b_out[0];
    float l1 = part[1][0] + b_out[1];
    float l2 = part[2][0] + b_out[2];
    float m = fmaxf(l0, fmaxf(l1, l2));
    float e0 = __expf(l0-m), e1 = __expf(l1-m), e2 = __expf(l2-m);
    float s = e0 + e1 + e2;
    out[b*3+0] = e0/s; out[b*3+1] = e1/s; out[b*3+2] = e2/s;
  }
}

extern "C" void kernel_launch(void* const* d_in, const int* in_sizes, int n_in,
                              void* d_out, int out_size, void* d_ws, size_t ws_size,
                              hipStream_t stream) {
  const float* x     = (const float*)d_in[0];
  const float* w_ih0 = (const float*)d_in[1];
  const float* w_hh0 = (const float*)d_in[2];
  const float* b0p   = (const float*)d_in[3];
  const float* w_ih1 = (const float*)d_in[4];
  const float* w_hh1 = (const float*)d_in[5];
  const float* b1p   = (const float*)d_in[6];
  const float* w_out = (const float*)d_in[7];
  const float* b_out = (const float*)d_in[8];
  float* out = (float*)d_out;

  // workspace (u16 units)
  unsigned short* y0    = (unsigned short*)d_ws;                    // 33,554,432
  unsigned short* xp1   = y0   + (size_t)T_LEN*BATCH*2*HID;         // 67,108,864
  unsigned short* wpack = xp1  + (size_t)T_LEN*BATCH*G4;            // 884,736
  unsigned short* wih1p = wpack + 3*WPACK_STRIDE;                   // 1,048,576
  float*          xp1b  = (float*)(wih1p + 2*G4*2*HID);             // 131,072 f32
  float*          hS    = xp1b + BATCH*G4;                          // 32,768 f32
  // exchange areas aliased into dead tails (y0 dead after gemms; xp1 tail dead
  // until gemm<0> writes it, which is after k_rec<0> completes)
  unsigned short* hx0   = xp1 + (size_t)T_LEN*BATCH*G4 - 16*4096;   // 16 grp x 4KB... (u16: 65536)
  unsigned*       cnt0  = (unsigned*)(hx0 - 64);                    // 16 flags
  unsigned short* hx1   = y0 + (size_t)T_LEN*BATCH*2*HID - 8*4096;  // 8 grp
  unsigned*       cnt1  = (unsigned*)(hx1 - 64);                    // 8 flags

  k_pack_rec<<<(3*WPACK_STRIDE + 255)/256, 256, 0, stream>>>(w_hh0, w_ih0, b0p, w_hh1, wpack);
  k_pack_wih1<<<(2*G4*2*HID + 255)/256, 256, 0, stream>>>(w_ih1, wih1p, 2*G4*2*HID);

  // layer 0, both directions, col-split x2
  hipMemsetAsync(cnt0, 0, 16*sizeof(unsigned), stream);
  k_rec<0><<<32, 256, 0, stream>>>(x, wpack, nullptr, y0, nullptr, cnt0, hx0);

  // layer-1 input projection (fwd dir), frag-packed bf16 out
  k_gemm_bf<0><<<dim3(8, 512), 256, 0, stream>>>(y0, wih1p, b1p, xp1, nullptr);

  // layer-1 backward first step gates: plain fp32
  k_gemm_bf<1><<<dim3(8, 1), 256, 0, stream>>>(y0 + (size_t)(T_LEN-1)*BATCH*2*HID,
                                               wih1p + (size_t)G4*2*HID, b1p + G4,
                                               nullptr, xp1b);

  // layer 1 forward recurrence, col-split x2
  hipMemsetAsync(cnt1, 0, 8*sizeof(unsigned), stream);
  k_rec<1><<<16, 256, 0, stream>>>(nullptr, wpack, xp1, nullptr, hS, cnt1, hx1);

  k_final<<<BATCH, 256, 0, stream>>>(hS, xp1b, w_out, b_out, out);
}

// Round 5
// 5075.748 us; speedup vs baseline: 3.4660x; 1.0842x over previous
//
#include <hip/hip_runtime.h>

typedef __attribute__((ext_vector_type(8))) short bf16x8;
typedef __attribute__((ext_vector_type(4))) float f32x4;

#define T_LEN 512
#define BATCH 128
#define HID   256
#define G4    1024
#define WPACK_STRIDE (16*4*9*64*8)   // 294912 bf16 per dir-layer

__device__ __forceinline__ float sigmf(float x){ return 1.0f/(1.0f + __expf(-x)); }
__device__ __forceinline__ float tanhf_(float x){ return 1.0f - 2.0f/(1.0f + __expf(2.0f*x)); }

__device__ __forceinline__ unsigned short f2bf(float f){
  union{float f;unsigned u;} v; v.f=f;
  unsigned r = v.u + 0x7FFF + ((v.u>>16)&1);
  return (unsigned short)(r>>16);
}
__device__ __forceinline__ float bf2f(unsigned short b){
  union{unsigned u;float f;} v; v.u = ((unsigned)b)<<16; return v.f;
}

// ---- pack recurrent weights into per-wave B-fragment stream order ----
// wpack[dl][w16:16][g:4][kk:9][lane:64][j:8]
// B[k][n]: n = g*256 + w16*16 + (lane&15), k = kk*32 + (lane>>4)*8 + j
__global__ void k_pack_rec(const float* __restrict__ w_hh0, const float* __restrict__ w_ih0,
                           const float* __restrict__ b0,    const float* __restrict__ w_hh1,
                           unsigned short* __restrict__ wpack){
  int idx = blockIdx.x*256 + threadIdx.x;
  if (idx >= 3*WPACK_STRIDE) return;
  int dl = idx / WPACK_STRIDE;
  int r  = idx % WPACK_STRIDE;
  int j    = r & 7;
  int lane = (r >> 3) & 63;
  int kk   = (r >> 9) % 9;
  int g    = (r / (9*512)) % 4;
  int w    = r / (4*9*512);
  int n = g*256 + w*16 + (lane & 15);
  int k = kk*32 + ((lane >> 4) << 3) + j;
  float val = 0.f;
  if (dl < 2){
    if (k < 256)       val = w_hh0[(dl*G4 + n)*HID + k];
    else if (k < 260)  val = w_ih0[(dl*G4 + n)*4 + (k - 256)];
    else if (k == 260) val = b0[dl*G4 + n];
  } else {
    if (k < 256) val = w_hh1[n*HID + k];
  }
  wpack[idx] = f2bf(val);
}

__global__ void k_pack_wih1(const float* __restrict__ w, unsigned short* __restrict__ o, int n){
  int idx = blockIdx.x*256 + threadIdx.x;
  if (idx < n) o[idx] = f2bf(w[idx]);
}

// ---- recurrence, column-split x2 with register-resident weights ----
// MODE 0: layer0 both dirs, 32 blocks. MODE 1: layer1 fwd, 16 blocks.
// Exchange: u32-packed payload (shfl-transposed), parity-double-buffered hx,
// per-step slot flags (no RMW).
template<int MODE>
__global__ __launch_bounds__(256, 1) void k_rec(
    const float* __restrict__ x,
    const unsigned short* __restrict__ wpack,
    const unsigned short* __restrict__ xp,
    unsigned short* __restrict__ y0,
    float* __restrict__ hS,
    unsigned* __restrict__ fl,                // [grp][cb][8] step-slot flags
    unsigned* __restrict__ hx32)              // [grp][slot2][cb][16][64] u32 payload
{
  const int tid  = threadIdx.x;
  const int lane = tid & 63;
  const int w    = tid >> 6;                  // wave 0..3
  const int bx   = blockIdx.x;
  const int cb   = bx & 1;                    // column half
  int dir, bgrp, grp;
  if (MODE == 0){ grp = bx >> 1; dir = grp >> 3; bgrp = grp & 7; }
  else          { grp = bx >> 1; dir = 0;        bgrp = grp;     }
  const int b0 = bgrp * 16;
  constexpr int KK = (MODE == 0) ? 9 : 8;
  const int wbase16 = cb*8 + w*2;             // first of this wave's 2 w16-slices

  __shared__ __align__(16) unsigned short A_lds[2][16*288];

  // ---- load this wave's B slice into registers, once ----
  const bf16x8* bw = (const bf16x8*)(wpack
      + ((MODE==0) ? dir*WPACK_STRIDE : 2*WPACK_STRIDE)
      + (size_t)wbase16*(4*9*512));
  bf16x8 breg[2][4][KK];
  #pragma unroll
  for (int p = 0; p < 2; ++p)
    #pragma unroll
    for (int g = 0; g < 4; ++g)
      #pragma unroll
      for (int kk = 0; kk < KK; ++kk)
        breg[p][g][kk] = bw[((p*4 + g)*9 + kk)*64 + lane];

  for (int i = tid; i < 2*16*288; i += 256) ((unsigned short*)A_lds)[i] = 0;
  __syncthreads();
  if (MODE == 0 && tid < 16){
    A_lds[0][tid*288 + 260] = 0x3F80;
    A_lds[1][tid*288 + 260] = 0x3F80;
    int t0 = dir ? (T_LEN-1) : 0;
    const float* xr = &x[((size_t)(b0 + tid)*T_LEN + t0)*4];
    A_lds[0][tid*288 + 256] = f2bf(xr[0]);
    A_lds[0][tid*288 + 257] = f2bf(xr[1]);
    A_lds[0][tid*288 + 258] = f2bf(xr[2]);
    A_lds[0][tid*288 + 259] = f2bf(xr[3]);
  }

  float c_reg[2][4];
  #pragma unroll
  for (int p = 0; p < 2; ++p)
    #pragma unroll
    for (int r = 0; r < 4; ++r) c_reg[p][r] = 0.f;

  const int arow = lane & 15;
  const int rb   = (lane >> 4) * 4;
  const int odd  = lane & 1;
  int jcol[2];
  jcol[0] = wbase16*16 + (lane & 15);
  jcol[1] = jcol[0] + 16;

  // MODE1 C-in prefetch (double-buffered regs)
  uint2 cinC[2][4], cinN[2][4];
  if (MODE == 1){
    #pragma unroll
    for (int p = 0; p < 2; ++p)
      #pragma unroll
      for (int g = 0; g < 4; ++g)
        cinC[p][g] = *(const uint2*)(xp +
          ((((size_t)0*8 + bgrp)*16 + (wbase16+p))*4 + g)*256 + lane*4);
  }

  const int pcb = cb ^ 1;

  for (int tt = 0; tt < T_LEN; ++tt){
    const int t = (MODE == 0 && dir) ? (T_LEN-1-tt) : tt;
    const unsigned short* Acur = A_lds[tt & 1];
    unsigned short* Anxt = (unsigned short*)A_lds[(tt + 1) & 1];

    __syncthreads();   // Acur fully assembled (own writes + partner copy)

    // A fragments
    bf16x8 a[KK];
    #pragma unroll
    for (int kk = 0; kk < KK; ++kk)
      a[kk] = *(const bf16x8*)&Acur[arow*288 + kk*32 + (lane>>4)*8];

    // init acc; issue next-step C-in loads (hidden under MFMA)
    f32x4 acc[2][4];
    #pragma unroll
    for (int p = 0; p < 2; ++p)
      #pragma unroll
      for (int g = 0; g < 4; ++g){
        if (MODE == 1){
          uint2 cv = cinC[p][g];
          acc[p][g] = (f32x4){bf2f((unsigned short)(cv.x & 0xFFFF)),
                              bf2f((unsigned short)(cv.x >> 16)),
                              bf2f((unsigned short)(cv.y & 0xFFFF)),
                              bf2f((unsigned short)(cv.y >> 16))};
        } else {
          acc[p][g] = (f32x4){0.f, 0.f, 0.f, 0.f};
        }
      }
    if (MODE == 1){
      int tn = (t + 1 < T_LEN) ? t + 1 : t;
      #pragma unroll
      for (int p = 0; p < 2; ++p)
        #pragma unroll
        for (int g = 0; g < 4; ++g)
          cinN[p][g] = *(const uint2*)(xp +
            ((((size_t)tn*8 + bgrp)*16 + (wbase16+p))*4 + g)*256 + lane*4);
    }

    // MFMA: B entirely from registers
    #pragma unroll
    for (int p = 0; p < 2; ++p)
      #pragma unroll
      for (int g = 0; g < 4; ++g)
        #pragma unroll
        for (int kk = 0; kk < KK; ++kk)
          acc[p][g] = __builtin_amdgcn_mfma_f32_16x16x32_bf16(a[kk], breg[p][g][kk], acc[p][g], 0, 0, 0);

    // elementwise h/c update; u32-packed exchange + y0 stores
    #pragma unroll
    for (int p = 0; p < 2; ++p){
      unsigned short hbv[4];
      float hvf[4];
      #pragma unroll
      for (int r = 0; r < 4; ++r){
        float iv = acc[p][0][r], fv = acc[p][1][r], gg = acc[p][2][r], ov = acc[p][3][r];
        float c  = sigmf(fv)*c_reg[p][r] + sigmf(iv)*tanhf_(gg);
        c_reg[p][r] = c;
        float h  = sigmf(ov)*tanhf_(c);
        hvf[r] = h;
        hbv[r] = f2bf(h);
        Anxt[(rb + r)*288 + jcol[p]] = hbv[r];
      }
      // in-register transpose to (row, col-pair) u32s via lane-pair exchange
      unsigned pk0 = (unsigned)hbv[0] | ((unsigned)hbv[1] << 16);
      unsigned pk1 = (unsigned)hbv[2] | ((unsigned)hbv[3] << 16);
      unsigned nb0 = (unsigned)__shfl_xor((int)pk0, 1, 64);
      unsigned nb1 = (unsigned)__shfl_xor((int)pk1, 1, 64);
      unsigned s0 = odd ? ((nb1 & 0xFFFFu) | (pk1 << 16))
                        : ((pk0 & 0xFFFFu) | (nb0 << 16));       // row rb + (odd?2:0)
      unsigned s1 = odd ? ((nb1 >> 16) | (pk1 & 0xFFFF0000u))
                        : ((pk0 >> 16) | (nb0 & 0xFFFF0000u));   // row rb + (odd?3:1)
      int r0 = rb + (odd ? 2 : 0);
      int cp = w*16 + p*8 + ((lane & 15) >> 1);                  // col-pair in own half
      if (tt < T_LEN-1){
        unsigned* hxb = hx32 + ((size_t)(grp*4 + (tt & 1)*2 + cb)*16)*64;
        __hip_atomic_store(&hxb[(r0    )*64 + cp], s0, __ATOMIC_RELAXED, __HIP_MEMORY_SCOPE_AGENT);
        __hip_atomic_store(&hxb[(r0 + 1)*64 + cp], s1, __ATOMIC_RELAXED, __HIP_MEMORY_SCOPE_AGENT);
      }
      if (MODE == 0){
        int colu = wbase16*16 + p*16 + ((lane & 15) & ~1);       // u32-aligned col
        *(unsigned*)&y0[((size_t)t*BATCH + (b0 + r0    ))*(2*HID) + dir*HID + colu] = s0;
        *(unsigned*)&y0[((size_t)t*BATCH + (b0 + r0 + 1))*(2*HID) + dir*HID + colu] = s1;
      } else if (tt == T_LEN-1){
        #pragma unroll
        for (int r = 0; r < 4; ++r)
          hS[(size_t)(b0 + rb + r)*HID + jcol[p]] = hvf[r];
      }
    }

    if (MODE == 0 && tid < 16){  // next x into Anxt tail
      int tn = dir ? (t > 0 ? t-1 : 0) : (t < T_LEN-1 ? t+1 : t);
      const float* xr = &x[((size_t)(b0 + tid)*T_LEN + tn)*4];
      Anxt[tid*288 + 256] = f2bf(xr[0]);
      Anxt[tid*288 + 257] = f2bf(xr[1]);
      Anxt[tid*288 + 258] = f2bf(xr[2]);
      Anxt[tid*288 + 259] = f2bf(xr[3]);
    }

    if (MODE == 1){
      #pragma unroll
      for (int p = 0; p < 2; ++p)
        #pragma unroll
        for (int g = 0; g < 4; ++g) cinC[p][g] = cinN[p][g];
    }

    if (tt < T_LEN-1){
      asm volatile("s_waitcnt vmcnt(0)" ::: "memory");  // own payload stores done
      __syncthreads();                                   // ...for ALL threads
      if (tid == 0){
        __hip_atomic_store(&fl[(grp*2 + cb)*8 + (tt & 7)], (unsigned)(tt + 1),
                           __ATOMIC_RELEASE, __HIP_MEMORY_SCOPE_AGENT);
        const unsigned tgt = (unsigned)(tt + 1);
        unsigned* pfl = &fl[(grp*2 + pcb)*8 + (tt & 7)];
        while (__hip_atomic_load(pfl, __ATOMIC_RELAXED, __HIP_MEMORY_SCOPE_AGENT) < tgt){}
        (void)__hip_atomic_load(pfl, __ATOMIC_ACQUIRE, __HIP_MEMORY_SCOPE_AGENT);
      }
      __syncthreads();
      // copy partner half into Anxt
      const unsigned* hxp = hx32 + ((size_t)(grp*4 + (tt & 1)*2 + pcb)*16)*64;
      #pragma unroll
      for (int rep = 0; rep < 4; ++rep){
        int li = tid + rep*256;
        int row = li >> 6, cp2 = li & 63;
        unsigned v = __hip_atomic_load(&hxp[row*64 + cp2],
                                       __ATOMIC_RELAXED, __HIP_MEMORY_SCOPE_AGENT);
        *(unsigned*)&Anxt[row*288 + pcb*128 + cp2*2] = v;
      }
    }
  }
}

// ---- bf16 MFMA GEMM: C[M][1024] = A[M][512] * B[1024][512]^T + bias ----
template<int PLAIN>
__global__ __launch_bounds__(256) void k_gemm_bf(
    const unsigned short* __restrict__ A, const unsigned short* __restrict__ B,
    const float* __restrict__ bias, unsigned short* __restrict__ outF, float* __restrict__ outP)
{
  __shared__ __align__(16) unsigned short As[128*64];
  __shared__ __align__(16) unsigned short Bs[128*64];
  const int tid  = threadIdx.x;
  const int lane = tid & 63;
  const int w = tid >> 6, wm = w >> 1, wn = w & 1;
  const int t  = blockIdx.y;
  const int n0 = blockIdx.x * 128;

  f32x4 acc[4][4];
  #pragma unroll
  for (int i = 0; i < 4; ++i)
    #pragma unroll
    for (int jx = 0; jx < 4; ++jx) acc[i][jx] = (f32x4){0.f,0.f,0.f,0.f};

  const int sr = tid >> 3;
  const int sq = tid & 7;

  for (int k0 = 0; k0 < 512; k0 += 64){
    #pragma unroll
    for (int it = 0; it < 4; ++it){
      int r = sr + it*32;
      uint4 av = *(const uint4*)&A[((size_t)t*128 + r)*512 + k0 + sq*8];
      uint4 bv = *(const uint4*)&B[((size_t)(n0 + r))*512 + k0 + sq*8];
      *(uint4*)&As[r*64 + (sq ^ (r & 7))*8] = av;
      *(uint4*)&Bs[r*64 + (sq ^ (r & 7))*8] = bv;
    }
    __syncthreads();
    bf16x8 af[4][2], bfv[4][2];
    #pragma unroll
    for (int mt = 0; mt < 4; ++mt)
      #pragma unroll
      for (int kk = 0; kk < 2; ++kk){
        int row = wm*64 + mt*16 + (lane & 15);
        af[mt][kk] = *(const bf16x8*)&As[row*64 + ((kk*4 + (lane>>4)) ^ (row & 7))*8];
      }
    #pragma unroll
    for (int nl = 0; nl < 4; ++nl)
      #pragma unroll
      for (int kk = 0; kk < 2; ++kk){
        int row = wn*64 + nl*16 + (lane & 15);
        bfv[nl][kk] = *(const bf16x8*)&Bs[row*64 + ((kk*4 + (lane>>4)) ^ (row & 7))*8];
      }
    #pragma unroll
    for (int mt = 0; mt < 4; ++mt)
      #pragma unroll
      for (int nl = 0; nl < 4; ++nl){
        acc[mt][nl] = __builtin_amdgcn_mfma_f32_16x16x32_bf16(af[mt][0], bfv[nl][0], acc[mt][nl], 0,0,0);
        acc[mt][nl] = __builtin_amdgcn_mfma_f32_16x16x32_bf16(af[mt][1], bfv[nl][1], acc[mt][nl], 0,0,0);
      }
    __syncthreads();
  }

  #pragma unroll
  for (int mt = 0; mt < 4; ++mt){
    #pragma unroll
    for (int nl = 0; nl < 4; ++nl){
      int ng = n0 + wn*64 + nl*16 + (lane & 15);
      float bv = bias[ng];
      f32x4 v = acc[mt][nl];
      if (PLAIN){
        int mrow = wm*64 + mt*16 + (lane >> 4)*4;
        #pragma unroll
        for (int r = 0; r < 4; ++r)
          outP[((size_t)t*128 + mrow + r)*G4 + ng] = v[r] + bv;
      } else {
        // frag-pack for k_rec<1>: [t][bgrp:8][w16:16][g:4][lane:64][r:4]
        int bgrp = wm*4 + mt;
        int wrec = (ng >> 4) & 15;
        int g    = ng >> 8;
        unsigned short hb[4];
        #pragma unroll
        for (int r = 0; r < 4; ++r) hb[r] = f2bf(v[r] + bv);
        *(uint2*)&outF[(((((size_t)t*8 + bgrp)*16 + wrec)*4 + g)*64 + lane)*4] = *(uint2*)hb;
      }
    }
  }
}

// ---- final: layer-1 bwd single step + combine + out proj + softmax ----
__global__ __launch_bounds__(256) void k_final(const float* __restrict__ hS,
                                               const float* __restrict__ xp1b,
                                               const float* __restrict__ w_out,
                                               const float* __restrict__ b_out,
                                               float* __restrict__ out)
{
  const int b = blockIdx.x, j = threadIdx.x;
  float iv = xp1b[b*G4 + 0*HID + j];
  float gv = xp1b[b*G4 + 2*HID + j];
  float ov = xp1b[b*G4 + 3*HID + j];
  float c  = sigmf(iv)*tanhf_(gv);
  float hb = sigmf(ov)*tanhf_(c);
  float last = hS[b*HID + j] + hb;

  __shared__ float part[3][256];
  part[0][j] = last * w_out[0*HID + j];
  part[1][j] = last * w_out[1*HID + j];
  part[2][j] = last * w_out[2*HID + j];
  __syncthreads();
  for (int s = 128; s > 0; s >>= 1){
    if (j < s){
      part[0][j] += part[0][j+s];
      part[1][j] += part[1][j+s];
      part[2][j] += part[2][j+s];
    }
    __syncthreads();
  }
  if (j == 0){
    float l0 = part[0][0] + b_out[0];
    float l1 = part[1][0] + b_out[1];
    float l2 = part[2][0] + b_out[2];
    float m = fmaxf(l0, fmaxf(l1, l2));
    float e0 = __expf(l0-m), e1 = __expf(l1-m), e2 = __expf(l2-m);
    float s = e0 + e1 + e2;
    out[b*3+0] = e0/s; out[b*3+1] = e1/s; out[b*3+2] = e2/s;
  }
}

extern "C" void kernel_launch(void* const* d_in, const int* in_sizes, int n_in,
                              void* d_out, int out_size, void* d_ws, size_t ws_size,
                              hipStream_t stream) {
  const float* x     = (const float*)d_in[0];
  const float* w_ih0 = (const float*)d_in[1];
  const float* w_hh0 = (const float*)d_in[2];
  const float* b0p   = (const float*)d_in[3];
  const float* w_ih1 = (const float*)d_in[4];
  const float* w_hh1 = (const float*)d_in[5];
  const float* b1p   = (const float*)d_in[6];
  const float* w_out = (const float*)d_in[7];
  const float* b_out = (const float*)d_in[8];
  float* out = (float*)d_out;

  // workspace (u16 units)
  unsigned short* y0    = (unsigned short*)d_ws;                    // 33,554,432
  unsigned short* xp1   = y0   + (size_t)T_LEN*BATCH*2*HID;         // 67,108,864
  unsigned short* wpack = xp1  + (size_t)T_LEN*BATCH*G4;            // 884,736
  unsigned short* wih1p = wpack + 3*WPACK_STRIDE;                   // 1,048,576
  float*          xp1b  = (float*)(wih1p + 2*G4*2*HID);             // 131,072 f32
  float*          hS    = xp1b + BATCH*G4;                          // 32,768 f32
  // exchange areas aliased into dead tails:
  //  MODE0: xp1 tail (xp1 written only after k_rec<0> completes)
  //  MODE1: y0 tail (y0 dead after the gemms)
  unsigned short* hx0u  = xp1 + (size_t)T_LEN*BATCH*G4 - 131072;    // 16 grp x 16KB
  unsigned*       fl0   = (unsigned*)(hx0u - 512);                  // 256 u32 flags
  unsigned short* hx1u  = y0 + (size_t)T_LEN*BATCH*2*HID - 65536;   // 8 grp x 16KB
  unsigned*       fl1   = (unsigned*)(hx1u - 256);                  // 128 u32 flags

  k_pack_rec<<<(3*WPACK_STRIDE + 255)/256, 256, 0, stream>>>(w_hh0, w_ih0, b0p, w_hh1, wpack);
  k_pack_wih1<<<(2*G4*2*HID + 255)/256, 256, 0, stream>>>(w_ih1, wih1p, 2*G4*2*HID);

  // layer 0, both directions, col-split x2
  hipMemsetAsync(fl0, 0, 256*sizeof(unsigned), stream);
  k_rec<0><<<32, 256, 0, stream>>>(x, wpack, nullptr, y0, nullptr, fl0, (unsigned*)hx0u);

  // layer-1 input projection (fwd dir), frag-packed bf16 out
  k_gemm_bf<0><<<dim3(8, 512), 256, 0, stream>>>(y0, wih1p, b1p, xp1, nullptr);

  // layer-1 backward first step gates: plain fp32
  k_gemm_bf<1><<<dim3(8, 1), 256, 0, stream>>>(y0 + (size_t)(T_LEN-1)*BATCH*2*HID,
                                               wih1p + (size_t)G4*2*HID, b1p + G4,
                                               nullptr, xp1b);

  // layer 1 forward recurrence, col-split x2
  hipMemsetAsync(fl1, 0, 128*sizeof(unsigned), stream);
  k_rec<1><<<16, 256, 0, stream>>>(nullptr, wpack, xp1, nullptr, hS, fl1, (unsigned*)hx1u);

  k_final<<<BATCH, 256, 0, stream>>>(hS, xp1b, w_out, b_out, out);
}

// Round 6
// 3479.110 us; speedup vs baseline: 5.0566x; 1.4589x over previous
//
#include <hip/hip_runtime.h>

typedef __attribute__((ext_vector_type(8))) short bf16x8;
typedef __attribute__((ext_vector_type(4))) float f32x4;

#define T_LEN 512
#define BATCH 128
#define HID   256
#define G4    1024
#define WPACK_STRIDE (16*4*9*64*8)   // 294912 bf16 per dir-layer

__device__ __forceinline__ float sigmf(float x){
  return __builtin_amdgcn_rcpf(1.0f + __expf(-x));
}
__device__ __forceinline__ float tanhf_(float x){
  return 1.0f - 2.0f*__builtin_amdgcn_rcpf(1.0f + __expf(2.0f*x));
}

__device__ __forceinline__ unsigned short f2bf(float f){
  union{float f;unsigned u;} v; v.f=f;
  unsigned r = v.u + 0x7FFF + ((v.u>>16)&1);
  return (unsigned short)(r>>16);
}
__device__ __forceinline__ float bf2f(unsigned short b){
  union{unsigned u;float f;} v; v.u = ((unsigned)b)<<16; return v.f;
}

// ---- pack recurrent weights into per-wave B-fragment stream order ----
// wpack[dl][w16:16][g:4][kk:9][lane:64][j:8]
// B[k][n]: n = g*256 + w16*16 + (lane&15), k = kk*32 + (lane>>4)*8 + j
__global__ void k_pack_rec(const float* __restrict__ w_hh0, const float* __restrict__ w_ih0,
                           const float* __restrict__ b0,    const float* __restrict__ w_hh1,
                           unsigned short* __restrict__ wpack){
  int idx = blockIdx.x*256 + threadIdx.x;
  if (idx >= 3*WPACK_STRIDE) return;
  int dl = idx / WPACK_STRIDE;
  int r  = idx % WPACK_STRIDE;
  int j    = r & 7;
  int lane = (r >> 3) & 63;
  int kk   = (r >> 9) % 9;
  int g    = (r / (9*512)) % 4;
  int w    = r / (4*9*512);
  int n = g*256 + w*16 + (lane & 15);
  int k = kk*32 + ((lane >> 4) << 3) + j;
  float val = 0.f;
  if (dl < 2){
    if (k < 256)       val = w_hh0[(dl*G4 + n)*HID + k];
    else if (k < 260)  val = w_ih0[(dl*G4 + n)*4 + (k - 256)];
    else if (k == 260) val = b0[dl*G4 + n];
  } else {
    if (k < 256) val = w_hh1[n*HID + k];
  }
  wpack[idx] = f2bf(val);
}

__global__ void k_pack_wih1(const float* __restrict__ w, unsigned short* __restrict__ o, int n){
  int idx = blockIdx.x*256 + threadIdx.x;
  if (idx < n) o[idx] = f2bf(w[idx]);
}

// ---- recurrence, column-split x2 with register-resident weights ----
// MODE 0: layer0 both dirs, 32 blocks. MODE 1: layer1 fwd, 16 blocks.
// Exchange: self-validating tagged u64 payload (tag = step+1 in high 32 bits),
// parity double-buffered; consumer polls partner words directly (1 RTT).
// Partner = bx ^ NGRP -> same XCD under round-robin mapping.
template<int MODE>
__global__ __launch_bounds__(256, 1) void k_rec(
    const float* __restrict__ x,
    const unsigned short* __restrict__ wpack,
    const unsigned short* __restrict__ xp,
    unsigned short* __restrict__ y0,
    float* __restrict__ hS,
    unsigned long long* __restrict__ hx64)    // [grp][slot:2][cb:2][16][64] u64
{
  const int tid  = threadIdx.x;
  const int lane = tid & 63;
  const int w    = tid >> 6;                  // wave 0..3
  const int bx   = blockIdx.x;
  constexpr int NGRP = (MODE == 0) ? 16 : 8;
  const int cb   = bx / NGRP;                 // column half
  const int grp  = bx % NGRP;
  int dir, bgrp;
  if (MODE == 0){ dir = grp >> 3; bgrp = grp & 7; }
  else          { dir = 0;        bgrp = grp;     }
  const int b0 = bgrp * 16;
  constexpr int KK = (MODE == 0) ? 9 : 8;
  const int wbase16 = cb*8 + w*2;             // first of this wave's 2 w16-slices

  __shared__ __align__(16) unsigned short A_lds[2][16*288];

  // ---- load this wave's B slice into registers, once ----
  const bf16x8* bw = (const bf16x8*)(wpack
      + ((MODE==0) ? dir*WPACK_STRIDE : 2*WPACK_STRIDE)
      + (size_t)wbase16*(4*9*512));
  bf16x8 breg[2][4][KK];
  #pragma unroll
  for (int p = 0; p < 2; ++p)
    #pragma unroll
    for (int g = 0; g < 4; ++g)
      #pragma unroll
      for (int kk = 0; kk < KK; ++kk)
        breg[p][g][kk] = bw[((p*4 + g)*9 + kk)*64 + lane];

  for (int i = tid; i < 2*16*288; i += 256) ((unsigned short*)A_lds)[i] = 0;
  __syncthreads();
  if (MODE == 0 && tid < 16){
    A_lds[0][tid*288 + 260] = 0x3F80;
    A_lds[1][tid*288 + 260] = 0x3F80;
    int t0 = dir ? (T_LEN-1) : 0;
    const float* xr = &x[((size_t)(b0 + tid)*T_LEN + t0)*4];
    A_lds[0][tid*288 + 256] = f2bf(xr[0]);
    A_lds[0][tid*288 + 257] = f2bf(xr[1]);
    A_lds[0][tid*288 + 258] = f2bf(xr[2]);
    A_lds[0][tid*288 + 259] = f2bf(xr[3]);
  }

  float c_reg[2][4];
  #pragma unroll
  for (int p = 0; p < 2; ++p)
    #pragma unroll
    for (int r = 0; r < 4; ++r) c_reg[p][r] = 0.f;

  const int arow = lane & 15;
  const int rb   = (lane >> 4) * 4;
  const int odd  = lane & 1;
  int jcol[2];
  jcol[0] = wbase16*16 + (lane & 15);
  jcol[1] = jcol[0] + 16;

  // MODE1 C-in prefetch (double-buffered regs)
  uint2 cinC[2][4], cinN[2][4];
  if (MODE == 1){
    #pragma unroll
    for (int p = 0; p < 2; ++p)
      #pragma unroll
      for (int g = 0; g < 4; ++g)
        cinC[p][g] = *(const uint2*)(xp +
          ((((size_t)0*8 + bgrp)*16 + (wbase16+p))*4 + g)*256 + lane*4);
  }

  const int pcb = cb ^ 1;

  for (int tt = 0; tt < T_LEN; ++tt){
    const int t = (MODE == 0 && dir) ? (T_LEN-1-tt) : tt;
    const unsigned short* Acur = A_lds[tt & 1];
    unsigned short* Anxt = (unsigned short*)A_lds[(tt + 1) & 1];

    __syncthreads();   // Acur fully assembled (own writes + partner copy)

    // A fragments
    bf16x8 a[KK];
    #pragma unroll
    for (int kk = 0; kk < KK; ++kk)
      a[kk] = *(const bf16x8*)&Acur[arow*288 + kk*32 + (lane>>4)*8];

    // init acc; issue next-step C-in loads (hidden under MFMA)
    f32x4 acc[2][4];
    #pragma unroll
    for (int p = 0; p < 2; ++p)
      #pragma unroll
      for (int g = 0; g < 4; ++g){
        if (MODE == 1){
          uint2 cv = cinC[p][g];
          acc[p][g] = (f32x4){bf2f((unsigned short)(cv.x & 0xFFFF)),
                              bf2f((unsigned short)(cv.x >> 16)),
                              bf2f((unsigned short)(cv.y & 0xFFFF)),
                              bf2f((unsigned short)(cv.y >> 16))};
        } else {
          acc[p][g] = (f32x4){0.f, 0.f, 0.f, 0.f};
        }
      }
    if (MODE == 1){
      int tn = (t + 1 < T_LEN) ? t + 1 : t;
      #pragma unroll
      for (int p = 0; p < 2; ++p)
        #pragma unroll
        for (int g = 0; g < 4; ++g)
          cinN[p][g] = *(const uint2*)(xp +
            ((((size_t)tn*8 + bgrp)*16 + (wbase16+p))*4 + g)*256 + lane*4);
    }

    // MFMA: B entirely from registers
    #pragma unroll
    for (int p = 0; p < 2; ++p)
      #pragma unroll
      for (int g = 0; g < 4; ++g)
        #pragma unroll
        for (int kk = 0; kk < KK; ++kk)
          acc[p][g] = __builtin_amdgcn_mfma_f32_16x16x32_bf16(a[kk], breg[p][g][kk], acc[p][g], 0, 0, 0);

    // elementwise h/c update; fire tagged payload FIRST, then y0/hS stores
    #pragma unroll
    for (int p = 0; p < 2; ++p){
      unsigned short hbv[4];
      float hvf[4];
      #pragma unroll
      for (int r = 0; r < 4; ++r){
        float iv = acc[p][0][r], fv = acc[p][1][r], gg = acc[p][2][r], ov = acc[p][3][r];
        float c  = sigmf(fv)*c_reg[p][r] + sigmf(iv)*tanhf_(gg);
        c_reg[p][r] = c;
        float h  = sigmf(ov)*tanhf_(c);
        hvf[r] = h;
        hbv[r] = f2bf(h);
        Anxt[(rb + r)*288 + jcol[p]] = hbv[r];
      }
      // in-register transpose to (row, col-pair) u32s via lane-pair exchange
      unsigned pk0 = (unsigned)hbv[0] | ((unsigned)hbv[1] << 16);
      unsigned pk1 = (unsigned)hbv[2] | ((unsigned)hbv[3] << 16);
      unsigned nb0 = (unsigned)__shfl_xor((int)pk0, 1, 64);
      unsigned nb1 = (unsigned)__shfl_xor((int)pk1, 1, 64);
      unsigned s0 = odd ? ((nb1 & 0xFFFFu) | (pk1 << 16))
                        : ((pk0 & 0xFFFFu) | (nb0 << 16));       // row rb + (odd?2:0)
      unsigned s1 = odd ? ((nb1 >> 16) | (pk1 & 0xFFFF0000u))
                        : ((pk0 >> 16) | (nb0 & 0xFFFF0000u));   // row rb + (odd?3:1)
      int r0 = rb + (odd ? 2 : 0);
      int cp = w*16 + p*8 + ((lane & 15) >> 1);                  // col-pair in own half
      if (tt < T_LEN-1){
        unsigned long long* hxb = hx64 + (size_t)(((grp*2 + (tt & 1))*2 + cb))*1024;
        unsigned long long tg = ((unsigned long long)(unsigned)(tt + 1)) << 32;
        __hip_atomic_store(&hxb[(r0    )*64 + cp], tg | s0,
                           __ATOMIC_RELAXED, __HIP_MEMORY_SCOPE_AGENT);
        __hip_atomic_store(&hxb[(r0 + 1)*64 + cp], tg | s1,
                           __ATOMIC_RELAXED, __HIP_MEMORY_SCOPE_AGENT);
      }
      if (MODE == 0){
        int colu = wbase16*16 + p*16 + ((lane & 15) & ~1);       // u32-aligned col
        *(unsigned*)&y0[((size_t)t*BATCH + (b0 + r0    ))*(2*HID) + dir*HID + colu] = s0;
        *(unsigned*)&y0[((size_t)t*BATCH + (b0 + r0 + 1))*(2*HID) + dir*HID + colu] = s1;
      } else if (tt == T_LEN-1){
        #pragma unroll
        for (int r = 0; r < 4; ++r)
          hS[(size_t)(b0 + rb + r)*HID + jcol[p]] = hvf[r];
      }
    }

    if (MODE == 0 && tid < 16){  // next x into Anxt tail
      int tn = dir ? (t > 0 ? t-1 : 0) : (t < T_LEN-1 ? t+1 : t);
      const float* xr = &x[((size_t)(b0 + tid)*T_LEN + tn)*4];
      Anxt[tid*288 + 256] = f2bf(xr[0]);
      Anxt[tid*288 + 257] = f2bf(xr[1]);
      Anxt[tid*288 + 258] = f2bf(xr[2]);
      Anxt[tid*288 + 259] = f2bf(xr[3]);
    }

    if (MODE == 1){
      #pragma unroll
      for (int p = 0; p < 2; ++p)
        #pragma unroll
        for (int g = 0; g < 4; ++g) cinC[p][g] = cinN[p][g];
    }

    // poll partner's tagged payload directly (data arrives with detection)
    if (tt < T_LEN-1){
      const unsigned long long* hxp = hx64 + (size_t)(((grp*2 + (tt & 1))*2 + pcb))*1024;
      const unsigned tag = (unsigned)(tt + 1);
      unsigned long long v[4];
      bool done[4] = {false, false, false, false};
      bool all;
      do {
        all = true;
        #pragma unroll
        for (int k = 0; k < 4; ++k){
          if (!done[k]){
            v[k] = __hip_atomic_load(&hxp[tid + k*256],
                                     __ATOMIC_RELAXED, __HIP_MEMORY_SCOPE_AGENT);
            done[k] = ((unsigned)(v[k] >> 32) == tag);
            if (!done[k]) all = false;
          }
        }
      } while (!all);
      #pragma unroll
      for (int k = 0; k < 4; ++k){
        int idx = tid + k*256;
        *(unsigned*)&Anxt[(idx >> 6)*288 + pcb*128 + (idx & 63)*2] = (unsigned)v[k];
      }
    }
  }
}

// ---- bf16 MFMA GEMM: C[M][1024] = A[M][512] * B[1024][512]^T + bias ----
template<int PLAIN>
__global__ __launch_bounds__(256) void k_gemm_bf(
    const unsigned short* __restrict__ A, const unsigned short* __restrict__ B,
    const float* __restrict__ bias, unsigned short* __restrict__ outF, float* __restrict__ outP)
{
  __shared__ __align__(16) unsigned short As[128*64];
  __shared__ __align__(16) unsigned short Bs[128*64];
  const int tid  = threadIdx.x;
  const int lane = tid & 63;
  const int w = tid >> 6, wm = w >> 1, wn = w & 1;
  const int t  = blockIdx.y;
  const int n0 = blockIdx.x * 128;

  f32x4 acc[4][4];
  #pragma unroll
  for (int i = 0; i < 4; ++i)
    #pragma unroll
    for (int jx = 0; jx < 4; ++jx) acc[i][jx] = (f32x4){0.f,0.f,0.f,0.f};

  const int sr = tid >> 3;
  const int sq = tid & 7;

  for (int k0 = 0; k0 < 512; k0 += 64){
    #pragma unroll
    for (int it = 0; it < 4; ++it){
      int r = sr + it*32;
      uint4 av = *(const uint4*)&A[((size_t)t*128 + r)*512 + k0 + sq*8];
      uint4 bv = *(const uint4*)&B[((size_t)(n0 + r))*512 + k0 + sq*8];
      *(uint4*)&As[r*64 + (sq ^ (r & 7))*8] = av;
      *(uint4*)&Bs[r*64 + (sq ^ (r & 7))*8] = bv;
    }
    __syncthreads();
    bf16x8 af[4][2], bfv[4][2];
    #pragma unroll
    for (int mt = 0; mt < 4; ++mt)
      #pragma unroll
      for (int kk = 0; kk < 2; ++kk){
        int row = wm*64 + mt*16 + (lane & 15);
        af[mt][kk] = *(const bf16x8*)&As[row*64 + ((kk*4 + (lane>>4)) ^ (row & 7))*8];
      }
    #pragma unroll
    for (int nl = 0; nl < 4; ++nl)
      #pragma unroll
      for (int kk = 0; kk < 2; ++kk){
        int row = wn*64 + nl*16 + (lane & 15);
        bfv[nl][kk] = *(const bf16x8*)&Bs[row*64 + ((kk*4 + (lane>>4)) ^ (row & 7))*8];
      }
    #pragma unroll
    for (int mt = 0; mt < 4; ++mt)
      #pragma unroll
      for (int nl = 0; nl < 4; ++nl){
        acc[mt][nl] = __builtin_amdgcn_mfma_f32_16x16x32_bf16(af[mt][0], bfv[nl][0], acc[mt][nl], 0,0,0);
        acc[mt][nl] = __builtin_amdgcn_mfma_f32_16x16x32_bf16(af[mt][1], bfv[nl][1], acc[mt][nl], 0,0,0);
      }
    __syncthreads();
  }

  #pragma unroll
  for (int mt = 0; mt < 4; ++mt){
    #pragma unroll
    for (int nl = 0; nl < 4; ++nl){
      int ng = n0 + wn*64 + nl*16 + (lane & 15);
      float bv = bias[ng];
      f32x4 v = acc[mt][nl];
      if (PLAIN){
        int mrow = wm*64 + mt*16 + (lane >> 4)*4;
        #pragma unroll
        for (int r = 0; r < 4; ++r)
          outP[((size_t)t*128 + mrow + r)*G4 + ng] = v[r] + bv;
      } else {
        // frag-pack for k_rec<1>: [t][bgrp:8][w16:16][g:4][lane:64][r:4]
        int bgrp = wm*4 + mt;
        int wrec = (ng >> 4) & 15;
        int g    = ng >> 8;
        unsigned short hb[4];
        #pragma unroll
        for (int r = 0; r < 4; ++r) hb[r] = f2bf(v[r] + bv);
        *(uint2*)&outF[(((((size_t)t*8 + bgrp)*16 + wrec)*4 + g)*64 + lane)*4] = *(uint2*)hb;
      }
    }
  }
}

// ---- final: layer-1 bwd single step + combine + out proj + softmax ----
__global__ __launch_bounds__(256) void k_final(const float* __restrict__ hS,
                                               const float* __restrict__ xp1b,
                                               const float* __restrict__ w_out,
                                               const float* __restrict__ b_out,
                                               float* __restrict__ out)
{
  const int b = blockIdx.x, j = threadIdx.x;
  float iv = xp1b[b*G4 + 0*HID + j];
  float gv = xp1b[b*G4 + 2*HID + j];
  float ov = xp1b[b*G4 + 3*HID + j];
  float c  = sigmf(iv)*tanhf_(gv);
  float hb = sigmf(ov)*tanhf_(c);
  float last = hS[b*HID + j] + hb;

  __shared__ float part[3][256];
  part[0][j] = last * w_out[0*HID + j];
  part[1][j] = last * w_out[1*HID + j];
  part[2][j] = last * w_out[2*HID + j];
  __syncthreads();
  for (int s = 128; s > 0; s >>= 1){
    if (j < s){
      part[0][j] += part[0][j+s];
      part[1][j] += part[1][j+s];
      part[2][j] += part[2][j+s];
    }
    __syncthreads();
  }
  if (j == 0){
    float l0 = part[0][0] + b_out[0];
    float l1 = part[1][0] + b_out[1];
    float l2 = part[2][0] + b_out[2];
    float m = fmaxf(l0, fmaxf(l1, l2));
    float e0 = __expf(l0-m), e1 = __expf(l1-m), e2 = __expf(l2-m);
    float s = e0 + e1 + e2;
    out[b*3+0] = e0/s; out[b*3+1] = e1/s; out[b*3+2] = e2/s;
  }
}

extern "C" void kernel_launch(void* const* d_in, const int* in_sizes, int n_in,
                              void* d_out, int out_size, void* d_ws, size_t ws_size,
                              hipStream_t stream) {
  const float* x     = (const float*)d_in[0];
  const float* w_ih0 = (const float*)d_in[1];
  const float* w_hh0 = (const float*)d_in[2];
  const float* b0p   = (const float*)d_in[3];
  const float* w_ih1 = (const float*)d_in[4];
  const float* w_hh1 = (const float*)d_in[5];
  const float* b1p   = (const float*)d_in[6];
  const float* w_out = (const float*)d_in[7];
  const float* b_out = (const float*)d_in[8];
  float* out = (float*)d_out;

  // workspace (u16 units)
  unsigned short* y0    = (unsigned short*)d_ws;                    // 33,554,432
  unsigned short* xp1   = y0   + (size_t)T_LEN*BATCH*2*HID;         // 67,108,864
  unsigned short* wpack = xp1  + (size_t)T_LEN*BATCH*G4;            // 884,736
  unsigned short* wih1p = wpack + 3*WPACK_STRIDE;                   // 1,048,576
  float*          xp1b  = (float*)(wih1p + 2*G4*2*HID);             // 131,072 f32
  float*          hS    = xp1b + BATCH*G4;                          // 32,768 f32
  // exchange areas aliased into dead tails:
  //  MODE0: xp1 tail (xp1 written only after k_rec<0> completes): 512 KB
  //  MODE1: y0 tail (y0 dead after the gemms): 256 KB
  unsigned long long* hx0 = (unsigned long long*)(xp1 + (size_t)T_LEN*BATCH*G4 - 262144);
  unsigned long long* hx1 = (unsigned long long*)(y0 + (size_t)T_LEN*BATCH*2*HID - 131072);

  k_pack_rec<<<(3*WPACK_STRIDE + 255)/256, 256, 0, stream>>>(w_hh0, w_ih0, b0p, w_hh1, wpack);
  k_pack_wih1<<<(2*G4*2*HID + 255)/256, 256, 0, stream>>>(w_ih1, wih1p, 2*G4*2*HID);

  // layer 0, both directions, col-split x2 (partner = bx ^ 16, same XCD)
  hipMemsetAsync(hx0, 0, 524288, stream);
  k_rec<0><<<32, 256, 0, stream>>>(x, wpack, nullptr, y0, nullptr, hx0);

  // layer-1 input projection (fwd dir), frag-packed bf16 out
  k_gemm_bf<0><<<dim3(8, 512), 256, 0, stream>>>(y0, wih1p, b1p, xp1, nullptr);

  // layer-1 backward first step gates: plain fp32
  k_gemm_bf<1><<<dim3(8, 1), 256, 0, stream>>>(y0 + (size_t)(T_LEN-1)*BATCH*2*HID,
                                               wih1p + (size_t)G4*2*HID, b1p + G4,
                                               nullptr, xp1b);

  // layer 1 forward recurrence, col-split x2 (partner = bx ^ 8, same XCD)
  hipMemsetAsync(hx1, 0, 262144, stream);
  k_rec<1><<<16, 256, 0, stream>>>(nullptr, wpack, xp1, nullptr, hS, hx1);

  k_final<<<BATCH, 256, 0, stream>>>(hS, xp1b, w_out, b_out, out);
}